// Round 1
// baseline (1269.144 us; speedup 1.0000x reference)
//
#include <hip/hip_runtime.h>
#include <stdint.h>

#define B_ 64
#define F2_ 256
#define J_ 25
#define FILT_ 64
#define C1_ 1600   // J*FILT
#define O1_ 128
#define NN_ 409600 // B*F*J
#define MM_ 16384  // B*F
#define EPSV 1e-5f

// ---- workspace layout (bytes) ----
static const size_t WS_Y2T = 0;                       // bf16 [B][C1][256] = 52,428,800
static const size_t WS_XA  = 52428800;                // f32  [NN][3]     =  4,915,200
static const size_t WS_Y3  = WS_XA + 4915200;         // f32  [B][O1][256]=  8,388,608
static const size_t WS_H3  = WS_Y3 + 8388608;         // f32  same
static const size_t WS_Y4  = WS_H3 + 8388608;         // f32  [B][256][64]=  4,194,304
static const size_t WS_ST  = WS_Y4 + 4194304;         // f32 stats block
// stats block float offsets
#define ST_S9    0
#define ST_SUM2  16
#define ST_SQ2   80
#define ST_SUM3  144
#define ST_SQ3   272
#define ST_SUM4  400
#define ST_SQ4   464
#define ST_S1    528
#define ST_T1    592
#define ST_SC2   656
#define ST_SH2   720
#define ST_SC3   784
#define ST_SH3   912
#define ST_SC4   1040
#define ST_SH4   1104
#define ST_COUNT 1168

__device__ __forceinline__ float bf2f(unsigned short u){
  return __uint_as_float(((unsigned int)u) << 16);
}
__device__ __forceinline__ unsigned short f2bf(float f){
  unsigned int u = __float_as_uint(f);
  u += 0x7fffu + ((u >> 16) & 1u);   // RNE
  return (unsigned short)(u >> 16);
}
__device__ __forceinline__ float lrelu(float x){ return fmaxf(x, 0.2f * x); }
__device__ __forceinline__ float wsum(float v){
  #pragma unroll
  for (int off = 32; off > 0; off >>= 1) v += __shfl_down(v, off, 64);
  return v;
}

// ---- GCN1 aggregate: xa[n] = sum_nbr norm * x, plus 9-scalar moment reduction ----
__global__ __launch_bounds__(256) void k_gcn1(const float* __restrict__ x,
                                              float* __restrict__ xa,
                                              float* __restrict__ S9){
  int n = blockIdx.x * 256 + threadIdx.x;      // N = 1600*256 exact
  int j = n % J_;
  float dj  = (j == 0 || j == J_-1) ? 2.f : 3.f;
  float rdj = rsqrtf(dj);
  const float* xp = x + (size_t)n * 3;
  float wg = 1.f / dj;                         // self-loop norm
  float a0 = xp[0]*wg, a1 = xp[1]*wg, a2 = xp[2]*wg;
  if (j > 0){
    float dm = (j == 1) ? 2.f : 3.f;  float w = rdj * rsqrtf(dm);
    a0 += xp[-3]*w; a1 += xp[-2]*w; a2 += xp[-1]*w;
  }
  if (j < J_-1){
    float dp = (j == J_-2) ? 2.f : 3.f;  float w = rdj * rsqrtf(dp);
    a0 += xp[3]*w; a1 += xp[4]*w; a2 += xp[5]*w;
  }
  float* xo = xa + (size_t)n * 3;
  xo[0] = a0; xo[1] = a1; xo[2] = a2;
  float p[9] = {a0, a1, a2, a0*a0, a0*a1, a0*a2, a1*a1, a1*a2, a2*a2};
  __shared__ float tmp[9][4];
  int wv = threadIdx.x >> 6, ln = threadIdx.x & 63;
  #pragma unroll
  for (int k = 0; k < 9; k++){ float s = wsum(p[k]); if (ln == 0) tmp[k][wv] = s; }
  __syncthreads();
  if (threadIdx.x < 9){
    int k = threadIdx.x;
    atomicAdd(S9 + k, tmp[k][0] + tmp[k][1] + tmp[k][2] + tmp[k][3]);
  }
}

// ---- BN1 params in closed form from moments ----
__global__ void k_bn1(const float* __restrict__ S9, const float* __restrict__ W1,
                      const float* __restrict__ b1, const float* __restrict__ g1,
                      const float* __restrict__ be1,
                      float* __restrict__ s1, float* __restrict__ t1){
  int c = threadIdx.x;
  float inv = 1.f / (float)NN_;
  float m0 = S9[0]*inv, m1 = S9[1]*inv, m2 = S9[2]*inv;
  float C00 = S9[3]*inv - m0*m0, C01 = S9[4]*inv - m0*m1, C02 = S9[5]*inv - m0*m2;
  float C11 = S9[6]*inv - m1*m1, C12 = S9[7]*inv - m1*m2, C22 = S9[8]*inv - m2*m2;
  float w0 = W1[c], w1 = W1[64+c], w2 = W1[128+c];
  float mean = m0*w0 + m1*w1 + m2*w2 + b1[c];
  float var  = w0*w0*C00 + w1*w1*C11 + w2*w2*C22
             + 2.f*(w0*w1*C01 + w0*w2*C02 + w1*w2*C12);
  float s = g1[c] * rsqrtf(var + EPSV);
  s1[c] = s;
  t1[c] = be1[c] - s*mean + s*b1[c];   // h1 = lrelu(s*(xa.w1c) + t1)
}

// ---- GCN2: recompute neighbor h1 from xa, aggregate, 64x64 GEMM, store bf16 transposed ----
__global__ __launch_bounds__(256) void k_gcn2(const float* __restrict__ xa,
                                              const float* __restrict__ W1,
                                              const float* __restrict__ s1,
                                              const float* __restrict__ t1,
                                              const float* __restrict__ W2,
                                              const float* __restrict__ b2,
                                              unsigned short* __restrict__ y2t){
  int bj = blockIdx.x; int b = bj / J_; int j = bj - b * J_;
  int l = threadIdx.x;                          // frame
  size_t n = ((size_t)(b * F2_ + l)) * J_ + j;
  const float* base = xa + n * 3;
  float xs0 = base[0], xs1 = base[1], xs2 = base[2];
  float xm0 = 0.f, xm1 = 0.f, xm2 = 0.f, xq0 = 0.f, xq1 = 0.f, xq2 = 0.f;
  float dj  = (j == 0 || j == J_-1) ? 2.f : 3.f;
  float rdj = rsqrtf(dj);
  float wgs = 1.f / dj, wgm = 0.f, wgp = 0.f;
  if (j > 0){ xm0 = base[-3]; xm1 = base[-2]; xm2 = base[-1];
              float dm = (j == 1) ? 2.f : 3.f;  wgm = rdj * rsqrtf(dm); }
  if (j < J_-1){ xq0 = base[3]; xq1 = base[4]; xq2 = base[5];
              float dp = (j == J_-2) ? 2.f : 3.f;  wgp = rdj * rsqrtf(dp); }
  float y[64];
  #pragma unroll
  for (int c = 0; c < 64; c++) y[c] = b2[c];
  for (int cc = 0; cc < 64; cc++){
    float w0 = W1[cc], w1 = W1[64+cc], w2 = W1[128+cc];
    float s = s1[cc], t = t1[cc];
    float hm = lrelu(fmaf(s, fmaf(xm0,w0, fmaf(xm1,w1, xm2*w2)), t));
    float hs = lrelu(fmaf(s, fmaf(xs0,w0, fmaf(xs1,w1, xs2*w2)), t));
    float hp = lrelu(fmaf(s, fmaf(xq0,w0, fmaf(xq1,w1, xq2*w2)), t));
    float a = wgm*hm + wgs*hs + wgp*hp;
    const float* wr = W2 + cc * 64;
    #pragma unroll
    for (int c = 0; c < 64; c++) y[c] = fmaf(a, wr[c], y[c]);
  }
  unsigned short* orow = y2t + ((((size_t)b * C1_) + j * 64) << 8) + l;
  #pragma unroll
  for (int f = 0; f < 64; f++) orow[(size_t)f << 8] = f2bf(y[f]);
}

// ---- per-channel stats of y2t (pre-BN2) ----
__global__ __launch_bounds__(1024) void k_stats2(const unsigned short* __restrict__ y2t,
                                                 float* __restrict__ sum2,
                                                 float* __restrict__ sq2){
  int f = blockIdx.x & 63; int bq = blockIdx.x >> 6;
  int l = threadIdx.x & 255; int q = threadIdx.x >> 8;
  float s = 0.f, sq = 0.f;
  int r0 = bq * 400 + q * 100;
  for (int i = 0; i < 100; i++){
    int r = r0 + i; int b = r / J_; int jj = r - b * J_;
    float v = bf2f(y2t[((((size_t)b * C1_) + jj * 64 + f) << 8) + l]);
    s += v; sq += v * v;
  }
  s = wsum(s); sq = wsum(sq);
  __shared__ float ts[16], tq[16];
  int wv = threadIdx.x >> 6, ln = threadIdx.x & 63;
  if (ln == 0){ ts[wv] = s; tq[wv] = sq; }
  __syncthreads();
  if (threadIdx.x == 0){
    float S = 0.f, Q = 0.f;
    for (int i = 0; i < 16; i++){ S += ts[i]; Q += tq[i]; }
    atomicAdd(sum2 + f, S); atomicAdd(sq2 + f, Q);
  }
}

// ---- generic BN param finalize: sc = g*rsqrt(var+eps), sh = be - sc*mean ----
__global__ void k_bnp(const float* __restrict__ sum, const float* __restrict__ sq,
                      const float* __restrict__ g, const float* __restrict__ be,
                      float* __restrict__ sc, float* __restrict__ sh, float inv){
  int c = threadIdx.x;
  float mean = sum[c] * inv;
  float var  = sq[c] * inv - mean * mean;
  float s = g[c] * rsqrtf(var + EPSV);
  sc[c] = s; sh[c] = be[c] - s * mean;
}

// ---- apply BN2+lrelu in place on y2t ----
__global__ __launch_bounds__(256) void k_bnapp2(unsigned short* __restrict__ y2t,
                                                const float* __restrict__ sc2,
                                                const float* __restrict__ sh2){
  for (size_t qq = (size_t)blockIdx.x * 256 + threadIdx.x; qq < 3276800u; qq += 524288u){
    int c = (int)((qq >> 5) % C1_); int f = c & 63;
    float sc = sc2[f], sh = sh2[f];
    uint4* p = (uint4*)(y2t) + qq;
    uint4 v = *p;
    unsigned int vv[4] = {v.x, v.y, v.z, v.w};
    unsigned int r[4];
    #pragma unroll
    for (int i = 0; i < 4; i++){
      float lo = __uint_as_float(vv[i] << 16);
      float hi = __uint_as_float(vv[i] & 0xffff0000u);
      lo = lrelu(fmaf(sc, lo, sh));
      hi = lrelu(fmaf(sc, hi, sh));
      r[i] = (unsigned int)f2bf(lo) | (((unsigned int)f2bf(hi)) << 16);
    }
    *p = make_uint4(r[0], r[1], r[2], r[3]);
  }
}

// ---- conv1: K=3 pad=1, 1600->128 channels; wave-per-o, 4 l per lane ----
__global__ __launch_bounds__(256) void k_conv1(const unsigned short* __restrict__ h2,
                                               const float* __restrict__ cw1,
                                               const float* __restrict__ cb1,
                                               float* __restrict__ y3){
  int blk = blockIdx.x; int b = blk >> 5; int og = blk & 31;
  int wv = threadIdx.x >> 6; int ln = threadIdx.x & 63;
  int o = og * 4 + wv;
  int os = __builtin_amdgcn_readfirstlane(o);
  int l0 = ln << 2;
  float a0, a1, a2, a3;
  a0 = a1 = a2 = a3 = cb1[os];
  const unsigned short* tb = h2 + (((size_t)b * C1_) << 8);
  const float* wb = cw1 + (size_t)os * 4800;
  for (int c = 0; c < C1_; c++){
    const unsigned short* trow = tb + ((size_t)c << 8);
    uint2 u = *(const uint2*)(trow + l0);
    float t0 = __uint_as_float(u.x << 16);
    float t1 = __uint_as_float(u.x & 0xffff0000u);
    float t2 = __uint_as_float(u.y << 16);
    float t3 = __uint_as_float(u.y & 0xffff0000u);
    float tm = (l0 > 0)   ? bf2f(trow[l0 - 1]) : 0.f;
    float tp = (l0 < 252) ? bf2f(trow[l0 + 4]) : 0.f;
    float w0 = wb[c*3 + 0], w1 = wb[c*3 + 1], w2 = wb[c*3 + 2];
    a0 = fmaf(w0, tm, fmaf(w1, t0, fmaf(w2, t1, a0)));
    a1 = fmaf(w0, t0, fmaf(w1, t1, fmaf(w2, t2, a1)));
    a2 = fmaf(w0, t1, fmaf(w1, t2, fmaf(w2, t3, a2)));
    a3 = fmaf(w0, t2, fmaf(w1, t3, fmaf(w2, tp, a3)));
  }
  float4* out = (float4*)(y3 + ((((size_t)b * O1_) + o) << 8) + l0);
  *out = make_float4(a0, a1, a2, a3);
}

// ---- stats of y3 per output channel o ----
__global__ __launch_bounds__(256) void k_stats3(const float* __restrict__ y3,
                                                float* __restrict__ sum3,
                                                float* __restrict__ sq3){
  int o = blockIdx.x; int l = threadIdx.x;
  float s = 0.f, q = 0.f;
  for (int b = 0; b < B_; b++){
    float v = y3[((((size_t)b * O1_) + o) << 8) + l];
    s += v; q += v * v;
  }
  s = wsum(s); q = wsum(q);
  __shared__ float ts[4], tq[4];
  int wv = threadIdx.x >> 6, ln = threadIdx.x & 63;
  if (ln == 0){ ts[wv] = s; tq[wv] = q; }
  __syncthreads();
  if (threadIdx.x == 0){
    sum3[o] = ts[0] + ts[1] + ts[2] + ts[3];
    sq3[o]  = tq[0] + tq[1] + tq[2] + tq[3];
  }
}

// ---- h3 = lrelu(bn3(y3)) ----
__global__ __launch_bounds__(256) void k_h3(const float* __restrict__ y3,
                                            const float* __restrict__ sc3,
                                            const float* __restrict__ sh3,
                                            float* __restrict__ h3){
  size_t q = (size_t)blockIdx.x * 256 + threadIdx.x;   // 524288 quads exactly
  int o = (int)((q >> 6) & 127);
  float sc = sc3[o], sh = sh3[o];
  float4 v = ((const float4*)y3)[q];
  v.x = lrelu(fmaf(sc, v.x, sh));
  v.y = lrelu(fmaf(sc, v.y, sh));
  v.z = lrelu(fmaf(sc, v.z, sh));
  v.w = lrelu(fmaf(sc, v.w, sh));
  ((float4*)h3)[q] = v;
}

// ---- conv2: K=1, 128->64 channels; writes y4 in [b][l][f] layout ----
__global__ __launch_bounds__(256) void k_conv2(const float* __restrict__ h3,
                                               const float* __restrict__ cw2,
                                               const float* __restrict__ cb2,
                                               float* __restrict__ y4){
  int blk = blockIdx.x; int b = blk >> 4; int fg = blk & 15;
  int wv = threadIdx.x >> 6, ln = threadIdx.x & 63;
  int f = fg * 4 + wv;
  int fs = __builtin_amdgcn_readfirstlane(f);
  int l0 = ln << 2;
  float a0, a1, a2, a3;
  a0 = a1 = a2 = a3 = cb2[fs];
  const float* hb = h3 + (((size_t)b * O1_) << 8) + l0;
  const float* wr = cw2 + (size_t)fs * O1_;
  for (int c = 0; c < O1_; c++){
    float4 h = *(const float4*)(hb + ((size_t)c << 8));
    float w = wr[c];
    a0 = fmaf(w, h.x, a0); a1 = fmaf(w, h.y, a1);
    a2 = fmaf(w, h.z, a2); a3 = fmaf(w, h.w, a3);
  }
  float* ob = y4 + (((size_t)b * F2_ + l0) << 6) + f;
  ob[0] = a0; ob[64] = a1; ob[128] = a2; ob[192] = a3;
}

// ---- stats of y4 per channel f ----
__global__ __launch_bounds__(1024) void k_stats4(const float* __restrict__ y4,
                                                 float* __restrict__ sum4,
                                                 float* __restrict__ sq4){
  int f = blockIdx.x;
  float s = 0.f, q = 0.f;
  for (int p = threadIdx.x; p < MM_; p += 1024){
    float v = y4[((size_t)p << 6) + f];
    s += v; q += v * v;
  }
  s = wsum(s); q = wsum(q);
  __shared__ float ts[16], tq[16];
  int wv = threadIdx.x >> 6, ln = threadIdx.x & 63;
  if (ln == 0){ ts[wv] = s; tq[wv] = q; }
  __syncthreads();
  if (threadIdx.x == 0){
    float S = 0.f, Q = 0.f;
    for (int i = 0; i < 16; i++){ S += ts[i]; Q += tq[i]; }
    sum4[f] = S; sq4[f] = Q;
  }
}

// ---- final: out = lrelu(bn4(y4)), already [b][l][f] ----
__global__ __launch_bounds__(256) void k_final(const float* __restrict__ y4,
                                               const float* __restrict__ sc4,
                                               const float* __restrict__ sh4,
                                               float* __restrict__ out){
  size_t q = (size_t)blockIdx.x * 256 + threadIdx.x;   // 262144 quads exactly
  int f0 = ((int)q & 15) << 2;
  float4 v = ((const float4*)y4)[q];
  float4 sc = *(const float4*)(sc4 + f0);
  float4 sh = *(const float4*)(sh4 + f0);
  v.x = lrelu(fmaf(sc.x, v.x, sh.x));
  v.y = lrelu(fmaf(sc.y, v.y, sh.y));
  v.z = lrelu(fmaf(sc.z, v.z, sh.z));
  v.w = lrelu(fmaf(sc.w, v.w, sh.w));
  ((float4*)out)[q] = v;
}

extern "C" void kernel_launch(void* const* d_in, const int* in_sizes, int n_in,
                              void* d_out, int out_size, void* d_ws, size_t ws_size,
                              hipStream_t stream){
  const float* x    = (const float*)d_in[0];
  // d_in[1] edge_index, d_in[2] batch_size, d_in[3] frame_l: topology is fixed, unused
  const float* W1   = (const float*)d_in[4];
  const float* b1   = (const float*)d_in[5];
  const float* g1   = (const float*)d_in[6];
  const float* be1  = (const float*)d_in[7];
  const float* W2   = (const float*)d_in[8];
  const float* b2   = (const float*)d_in[9];
  const float* g2   = (const float*)d_in[10];
  const float* be2  = (const float*)d_in[11];
  const float* cw1  = (const float*)d_in[12];
  const float* cb1  = (const float*)d_in[13];
  const float* cg1  = (const float*)d_in[14];
  const float* cbe1 = (const float*)d_in[15];
  const float* cw2  = (const float*)d_in[16];
  const float* cb2  = (const float*)d_in[17];
  const float* cg2  = (const float*)d_in[18];
  const float* cbe2 = (const float*)d_in[19];

  char* ws = (char*)d_ws;
  unsigned short* y2t = (unsigned short*)(ws + WS_Y2T);
  float* xa = (float*)(ws + WS_XA);
  float* y3 = (float*)(ws + WS_Y3);
  float* h3 = (float*)(ws + WS_H3);
  float* y4 = (float*)(ws + WS_Y4);
  float* st = (float*)(ws + WS_ST);

  if (ws_size < WS_ST + ST_COUNT * 4) return;  // need ~78.4 MB scratch

  hipMemsetAsync(st, 0, ST_COUNT * 4, stream);
  k_gcn1  <<<1600, 256, 0, stream>>>(x, xa, st + ST_S9);
  k_bn1   <<<1, 64, 0, stream>>>(st + ST_S9, W1, b1, g1, be1, st + ST_S1, st + ST_T1);
  k_gcn2  <<<1600, 256, 0, stream>>>(xa, W1, st + ST_S1, st + ST_T1, W2, b2, y2t);
  k_stats2<<<256, 1024, 0, stream>>>(y2t, st + ST_SUM2, st + ST_SQ2);
  k_bnp   <<<1, 64, 0, stream>>>(st + ST_SUM2, st + ST_SQ2, g2, be2,
                                 st + ST_SC2, st + ST_SH2, 1.f / (float)NN_);
  k_bnapp2<<<2048, 256, 0, stream>>>(y2t, st + ST_SC2, st + ST_SH2);
  k_conv1 <<<2048, 256, 0, stream>>>(y2t, cw1, cb1, y3);
  k_stats3<<<128, 256, 0, stream>>>(y3, st + ST_SUM3, st + ST_SQ3);
  k_bnp   <<<1, 128, 0, stream>>>(st + ST_SUM3, st + ST_SQ3, cg1, cbe1,
                                  st + ST_SC3, st + ST_SH3, 1.f / (float)MM_);
  k_h3    <<<2048, 256, 0, stream>>>(y3, st + ST_SC3, st + ST_SH3, h3);
  k_conv2 <<<1024, 256, 0, stream>>>(h3, cw2, cb2, y4);
  k_stats4<<<64, 1024, 0, stream>>>(y4, st + ST_SUM4, st + ST_SQ4);
  k_bnp   <<<1, 64, 0, stream>>>(st + ST_SUM4, st + ST_SQ4, cg2, cbe2,
                                 st + ST_SC4, st + ST_SH4, 1.f / (float)MM_);
  k_final <<<1024, 256, 0, stream>>>(y4, st + ST_SC4, st + ST_SH4, (float*)d_out);
}

// Round 2
// 254.904 us; speedup vs baseline: 4.9789x; 4.9789x over previous
//
#include <hip/hip_runtime.h>
#include <stdint.h>

#define B_ 64
#define F2_ 256
#define J_ 25
#define FILT_ 64
#define C1_ 1600   // J*FILT
#define O1_ 128
#define NN_ 409600 // B*F*J
#define MM_ 16384  // B*F
#define EPSV 1e-5f

typedef short short8 __attribute__((ext_vector_type(8)));
typedef float f32x4 __attribute__((ext_vector_type(4)));

// ---- workspace layout (bytes) ----
// y2t: bf16 [64][258][1600]  (rows 0 and 257 per batch are zero pads)
static const size_t WS_Y2T = 0;                       // 52,838,400
static const size_t WS_XA  = 52838400;                // f32 [NN][3] 4,915,200
static const size_t WS_WT1 = 57753600;                // bf16 [3][128][1600] 1,228,800
static const size_t WS_WT2 = 58982400;                // bf16 [64][128] 16,384
static const size_t WS_Y3  = 58998784;                // f32 [64][256][128] 8,388,608
static const size_t WS_H3  = 67387392;                // bf16 [64][256][128] 4,194,304
static const size_t WS_Y4  = 71581696;                // f32 [64][256][64] 4,194,304
static const size_t WS_ST  = 75776000;                // f32 stats block
// stats block float offsets
#define ST_S9    0
#define ST_SUM2  16
#define ST_SQ2   80
#define ST_SUM3  144
#define ST_SQ3   272
#define ST_SUM4  400
#define ST_SQ4   464
#define ST_S1    528
#define ST_T1    592
#define ST_SC2   656
#define ST_SH2   720
#define ST_SC3   784
#define ST_SH3   912
#define ST_SC4   1040
#define ST_SH4   1104
#define ST_COUNT 1168

__device__ __forceinline__ float bf2f(unsigned int u){
  return __uint_as_float(u << 16);
}
__device__ __forceinline__ unsigned short f2bf(float f){
  unsigned int u = __float_as_uint(f);
  u += 0x7fffu + ((u >> 16) & 1u);   // RNE
  return (unsigned short)(u >> 16);
}
__device__ __forceinline__ float lrelu(float x){ return fmaxf(x, 0.2f * x); }
__device__ __forceinline__ float wsum(float v){
  #pragma unroll
  for (int off = 32; off > 0; off >>= 1) v += __shfl_down(v, off, 64);
  return v;
}

typedef __attribute__((address_space(3))) unsigned int lds_uint_t;
typedef __attribute__((address_space(1))) const unsigned int glob_uint_t;
__device__ __forceinline__ void gl16(const void* g, void* l){
  __builtin_amdgcn_global_load_lds((glob_uint_t*)g, (lds_uint_t*)l, 16, 0, 0);
}

// ---- zero the pad rows of y2t (rows 0 and 257 of each batch) ----
__global__ __launch_bounds__(256) void k_zpad(unsigned short* __restrict__ y2t){
  int b = blockIdx.x, tid = threadIdx.x;
  if (tid < 200){
    uint4 z = make_uint4(0,0,0,0);
    ((uint4*)(y2t + (size_t)b * 412800))[tid] = z;
    ((uint4*)(y2t + (size_t)b * 412800 + 257 * 1600))[tid] = z;
  }
}

// ---- weight transform: cw1 (O,I,3) f32 -> wt1[k][o][c] bf16; cw2 (64,128) -> wt2 bf16 ----
__global__ __launch_bounds__(256) void k_wt(const float* __restrict__ cw1,
                                            const float* __restrict__ cw2,
                                            unsigned short* __restrict__ wt1,
                                            unsigned short* __restrict__ wt2){
  int blk = blockIdx.x;
  if (blk < 384){
    int k = blk >> 7, o = blk & 127;
    for (int c = threadIdx.x; c < 1600; c += 256)
      wt1[(size_t)(k * 128 + o) * 1600 + c] = f2bf(cw1[(size_t)(o * 1600 + c) * 3 + k]);
  } else {
    int idx = ((blk - 384) << 8) + threadIdx.x;   // 32 blocks * 256 = 8192
    wt2[idx] = f2bf(cw2[idx]);
  }
}

// ---- GCN1 aggregate + 9-scalar moments ----
__global__ __launch_bounds__(256) void k_gcn1(const float* __restrict__ x,
                                              float* __restrict__ xa,
                                              float* __restrict__ S9){
  int n = blockIdx.x * 256 + threadIdx.x;
  int j = n % J_;
  float dj  = (j == 0 || j == J_-1) ? 2.f : 3.f;
  float rdj = rsqrtf(dj);
  const float* xp = x + (size_t)n * 3;
  float wg = 1.f / dj;
  float a0 = xp[0]*wg, a1 = xp[1]*wg, a2 = xp[2]*wg;
  if (j > 0){
    float dm = (j == 1) ? 2.f : 3.f;  float w = rdj * rsqrtf(dm);
    a0 += xp[-3]*w; a1 += xp[-2]*w; a2 += xp[-1]*w;
  }
  if (j < J_-1){
    float dp = (j == J_-2) ? 2.f : 3.f;  float w = rdj * rsqrtf(dp);
    a0 += xp[3]*w; a1 += xp[4]*w; a2 += xp[5]*w;
  }
  float* xo = xa + (size_t)n * 3;
  xo[0] = a0; xo[1] = a1; xo[2] = a2;
  float p[9] = {a0, a1, a2, a0*a0, a0*a1, a0*a2, a1*a1, a1*a2, a2*a2};
  __shared__ float tmp[9][4];
  int wv = threadIdx.x >> 6, ln = threadIdx.x & 63;
  #pragma unroll
  for (int k = 0; k < 9; k++){ float s = wsum(p[k]); if (ln == 0) tmp[k][wv] = s; }
  __syncthreads();
  if (threadIdx.x < 9){
    int k = threadIdx.x;
    atomicAdd(S9 + k, tmp[k][0] + tmp[k][1] + tmp[k][2] + tmp[k][3]);
  }
}

__global__ void k_bn1(const float* __restrict__ S9, const float* __restrict__ W1,
                      const float* __restrict__ b1, const float* __restrict__ g1,
                      const float* __restrict__ be1,
                      float* __restrict__ s1, float* __restrict__ t1){
  int c = threadIdx.x;
  float inv = 1.f / (float)NN_;
  float m0 = S9[0]*inv, m1 = S9[1]*inv, m2 = S9[2]*inv;
  float C00 = S9[3]*inv - m0*m0, C01 = S9[4]*inv - m0*m1, C02 = S9[5]*inv - m0*m2;
  float C11 = S9[6]*inv - m1*m1, C12 = S9[7]*inv - m1*m2, C22 = S9[8]*inv - m2*m2;
  float w0 = W1[c], w1 = W1[64+c], w2 = W1[128+c];
  float mean = m0*w0 + m1*w1 + m2*w2 + b1[c];
  float var  = w0*w0*C00 + w1*w1*C11 + w2*w2*C22
             + 2.f*(w0*w1*C01 + w0*w2*C02 + w1*w2*C12);
  float s = g1[c] * rsqrtf(var + EPSV);
  s1[c] = s;
  t1[c] = be1[c] - s*mean + s*b1[c];
}

// ---- GCN2: write bf16 rows [b][l+1][j*64+f] (c contiguous) ----
__global__ __launch_bounds__(256) void k_gcn2(const float* __restrict__ xa,
                                              const float* __restrict__ W1,
                                              const float* __restrict__ s1,
                                              const float* __restrict__ t1,
                                              const float* __restrict__ W2,
                                              const float* __restrict__ b2,
                                              unsigned short* __restrict__ y2t){
  int bj = blockIdx.x; int b = bj / J_; int j = bj - b * J_;
  int l = threadIdx.x;
  size_t n = ((size_t)(b * F2_ + l)) * J_ + j;
  const float* base = xa + n * 3;
  float xs0 = base[0], xs1 = base[1], xs2 = base[2];
  float xm0 = 0.f, xm1 = 0.f, xm2 = 0.f, xq0 = 0.f, xq1 = 0.f, xq2 = 0.f;
  float dj  = (j == 0 || j == J_-1) ? 2.f : 3.f;
  float rdj = rsqrtf(dj);
  float wgs = 1.f / dj, wgm = 0.f, wgp = 0.f;
  if (j > 0){ xm0 = base[-3]; xm1 = base[-2]; xm2 = base[-1];
              float dm = (j == 1) ? 2.f : 3.f;  wgm = rdj * rsqrtf(dm); }
  if (j < J_-1){ xq0 = base[3]; xq1 = base[4]; xq2 = base[5];
              float dp = (j == J_-2) ? 2.f : 3.f;  wgp = rdj * rsqrtf(dp); }
  float y[64];
  #pragma unroll
  for (int c = 0; c < 64; c++) y[c] = b2[c];
  for (int cc = 0; cc < 64; cc++){
    float w0 = W1[cc], w1 = W1[64+cc], w2 = W1[128+cc];
    float s = s1[cc], t = t1[cc];
    float hm = lrelu(fmaf(s, fmaf(xm0,w0, fmaf(xm1,w1, xm2*w2)), t));
    float hs = lrelu(fmaf(s, fmaf(xs0,w0, fmaf(xs1,w1, xs2*w2)), t));
    float hp = lrelu(fmaf(s, fmaf(xq0,w0, fmaf(xq1,w1, xq2*w2)), t));
    float a = wgm*hm + wgs*hs + wgp*hp;
    const float* wr = W2 + cc * 64;
    #pragma unroll
    for (int c = 0; c < 64; c++) y[c] = fmaf(a, wr[c], y[c]);
  }
  unsigned short* orow = y2t + ((size_t)(b * 258 + l + 1)) * 1600 + j * 64;
  uint4* op = (uint4*)orow;
  #pragma unroll
  for (int i = 0; i < 8; i++){
    uint4 u;
    u.x = (unsigned)f2bf(y[i*8+0]) | ((unsigned)f2bf(y[i*8+1]) << 16);
    u.y = (unsigned)f2bf(y[i*8+2]) | ((unsigned)f2bf(y[i*8+3]) << 16);
    u.z = (unsigned)f2bf(y[i*8+4]) | ((unsigned)f2bf(y[i*8+5]) << 16);
    u.w = (unsigned)f2bf(y[i*8+6]) | ((unsigned)f2bf(y[i*8+7]) << 16);
    op[i] = u;
  }
}

// ---- per-f stats of y2t (pads are zero -> harmless; divide by NN_) ----
__global__ __launch_bounds__(256) void k_stats2(const unsigned short* __restrict__ y2t,
                                                float* __restrict__ sum2,
                                                float* __restrict__ sq2){
  __shared__ float S[64], Q[64];
  int tid = threadIdx.x;
  if (tid < 64){ S[tid] = 0.f; Q[tid] = 0.f; }
  __syncthreads();
  float s[4] = {0,0,0,0}, q[4] = {0,0,0,0};
  const uint2* p = (const uint2*)y2t;
  for (unsigned g = blockIdx.x * 256 + tid; g < 6604800u; g += 262144u){
    uint2 u = p[g];
    float v0 = bf2f(u.x & 0xffffu), v1 = bf2f(u.x >> 16);
    float v2 = bf2f(u.y & 0xffffu), v3 = bf2f(u.y >> 16);
    s[0]+=v0; q[0]+=v0*v0; s[1]+=v1; q[1]+=v1*v1;
    s[2]+=v2; q[2]+=v2*v2; s[3]+=v3; q[3]+=v3*v3;
  }
  int f0 = (tid << 2) & 63;
  #pragma unroll
  for (int i = 0; i < 4; i++){ atomicAdd(&S[f0+i], s[i]); atomicAdd(&Q[f0+i], q[i]); }
  __syncthreads();
  if (tid < 64){ atomicAdd(sum2 + tid, S[tid]); atomicAdd(sq2 + tid, Q[tid]); }
}

__global__ void k_bnp(const float* __restrict__ sum, const float* __restrict__ sq,
                      const float* __restrict__ g, const float* __restrict__ be,
                      float* __restrict__ sc, float* __restrict__ sh, float inv){
  int c = threadIdx.x;
  float mean = sum[c] * inv;
  float var  = sq[c] * inv - mean * mean;
  float s = g[c] * rsqrtf(var + EPSV);
  sc[c] = s; sh[c] = be[c] - s * mean;
}

// ---- apply BN2+lrelu in place on y2t data rows only (pads stay zero) ----
__global__ __launch_bounds__(256) void k_bnapp2(unsigned short* __restrict__ y2t,
                                                const float* __restrict__ sc2,
                                                const float* __restrict__ sh2){
  for (unsigned idx = blockIdx.x * 256 + threadIdx.x; idx < 3276800u; idx += 524288u){
    unsigned b = idx / 51200u;
    unsigned rem = idx - b * 51200u;
    unsigned l = rem / 200u;
    unsigned cg = rem - l * 200u;
    uint4* p = (uint4*)y2t + ((size_t)b * 258 + l + 1) * 200 + cg;
    unsigned f0 = (cg << 3) & 63u;
    float4 sa = *(const float4*)(sc2 + f0);
    float4 sb = *(const float4*)(sc2 + f0 + 4);
    float4 ha = *(const float4*)(sh2 + f0);
    float4 hb = *(const float4*)(sh2 + f0 + 4);
    float scs[8] = {sa.x,sa.y,sa.z,sa.w,sb.x,sb.y,sb.z,sb.w};
    float shs[8] = {ha.x,ha.y,ha.z,ha.w,hb.x,hb.y,hb.z,hb.w};
    uint4 v = *p;
    unsigned vv[4] = {v.x,v.y,v.z,v.w};
    unsigned r[4];
    #pragma unroll
    for (int i = 0; i < 4; i++){
      float lo = bf2f(vv[i] & 0xffffu);
      float hi = bf2f(vv[i] >> 16);
      lo = lrelu(fmaf(scs[2*i],   lo, shs[2*i]));
      hi = lrelu(fmaf(scs[2*i+1], hi, shs[2*i+1]));
      r[i] = (unsigned)f2bf(lo) | (((unsigned)f2bf(hi)) << 16);
    }
    *p = make_uint4(r[0],r[1],r[2],r[3]);
  }
}

// ---- conv1 as MFMA GEMM: per block (b, l-quarter, o-half): M=64 l, N=64 o, K=3*1600 ----
#define NT_ 75
__global__ __launch_bounds__(256) void k_conv1(const unsigned short* __restrict__ y2t,
                                               const unsigned short* __restrict__ wt1,
                                               const float* __restrict__ cb1,
                                               float* __restrict__ y3){
  __shared__ char smem[32768];   // As[2]:8KB, Bs[2]:8KB per buf (A at +0, B at +8192)
  int blk = blockIdx.x;          // 512 = 64b * 4lq * 2og
  int b  = blk >> 3;
  int lq = (blk >> 1) & 3;
  int og = blk & 1;
  int l0 = lq << 6;
  int tid = threadIdx.x;
  int w = tid >> 6, lane = tid & 63;
  int wm = w >> 1, wn = w & 1;   // 2x2 waves, wave tile 32x32
  const unsigned short* y2b = y2t + (size_t)b * 412800;
  const unsigned short* wtb = wt1 + (size_t)og * 64 * 1600;

  int rs = (w << 4) + (lane >> 3);   // staging rows rs, rs+8
  int cblk = lane & 7;

  int m0 = (wm << 5) + (lane & 15);
  int n0 = (wn << 5) + (lane & 15);
  int kg = lane >> 4;

  f32x4 acc[2][2] = {};

  auto stage = [&](int t, int buf){
    int k = t / 25;
    int cc = (t - k * 25) << 6;
    const unsigned short* wk = wtb + (size_t)k * 204800;
    #pragma unroll
    for (int i = 0; i < 2; i++){
      int r = rs + (i << 3);
      int sw = (cblk ^ (r & 7)) << 3;
      gl16(y2b + (size_t)(l0 + r + k) * 1600 + cc + sw,
           smem + buf * 16384 + (w << 11) + (i << 10));
      gl16(wk + (size_t)r * 1600 + cc + sw,
           smem + buf * 16384 + 8192 + (w << 11) + (i << 10));
    }
  };

  stage(0, 0);
  __syncthreads();
  #pragma unroll 2
  for (int t = 0; t < NT_; ++t){
    int buf = t & 1;
    if (t + 1 < NT_) stage(t + 1, buf ^ 1);
    const char* Ab = smem + buf * 16384;
    const char* Bb = Ab + 8192;
    #pragma unroll
    for (int ks = 0; ks < 2; ks++){
      int kb = kg + (ks << 2);
      short8 a0 = *(const short8*)(Ab + (m0 << 7)        + ((kb ^ (m0 & 7)) << 4));
      short8 a1 = *(const short8*)(Ab + ((m0 + 16) << 7) + ((kb ^ (m0 & 7)) << 4));
      short8 b0 = *(const short8*)(Bb + (n0 << 7)        + ((kb ^ (n0 & 7)) << 4));
      short8 b1 = *(const short8*)(Bb + ((n0 + 16) << 7) + ((kb ^ (n0 & 7)) << 4));
      acc[0][0] = __builtin_amdgcn_mfma_f32_16x16x32_bf16(a0, b0, acc[0][0], 0, 0, 0);
      acc[0][1] = __builtin_amdgcn_mfma_f32_16x16x32_bf16(a0, b1, acc[0][1], 0, 0, 0);
      acc[1][0] = __builtin_amdgcn_mfma_f32_16x16x32_bf16(a1, b0, acc[1][0], 0, 0, 0);
      acc[1][1] = __builtin_amdgcn_mfma_f32_16x16x32_bf16(a1, b1, acc[1][1], 0, 0, 0);
    }
    __syncthreads();
  }

  int colb = (og << 6) + n0;
  int rowb = l0 + (wm << 5) + ((lane >> 4) << 2);
  #pragma unroll
  for (int mi = 0; mi < 2; mi++){
    #pragma unroll
    for (int ni = 0; ni < 2; ni++){
      int col = colb + (ni << 4);
      float bias = cb1[col];
      #pragma unroll
      for (int r = 0; r < 4; r++){
        y3[(size_t)((b << 8) + rowb + (mi << 4) + r) * 128 + col] = acc[mi][ni][r] + bias;
      }
    }
  }
}

// ---- per-o stats of y3 [row][128] ----
__global__ __launch_bounds__(256) void k_stats3(const float* __restrict__ y3,
                                                float* __restrict__ sum3,
                                                float* __restrict__ sq3){
  __shared__ float S[128], Q[128];
  int tid = threadIdx.x;
  if (tid < 128){ S[tid] = 0.f; Q[tid] = 0.f; }
  __syncthreads();
  int o = tid & 127, half = tid >> 7;
  float s = 0.f, q = 0.f;
  int r0 = blockIdx.x << 8;
  for (int i = 0; i < 128; i++){
    float v = y3[(size_t)(r0 + (i << 1) + half) * 128 + o];
    s += v; q += v * v;
  }
  atomicAdd(&S[o], s); atomicAdd(&Q[o], q);
  __syncthreads();
  if (tid < 128){ atomicAdd(sum3 + tid, S[tid]); atomicAdd(sq3 + tid, Q[tid]); }
}

// ---- h3 = bf16(lrelu(bn3(y3))) ----
__global__ __launch_bounds__(256) void k_h3(const float* __restrict__ y3,
                                            const float* __restrict__ sc3,
                                            const float* __restrict__ sh3,
                                            unsigned short* __restrict__ h3){
  unsigned q = blockIdx.x * 256 + threadIdx.x;   // 524288 exact
  unsigned o0 = (q & 31) << 2;
  float4 v = ((const float4*)y3)[q];
  float4 sc = *(const float4*)(sc3 + o0);
  float4 sh = *(const float4*)(sh3 + o0);
  float r0 = lrelu(fmaf(sc.x, v.x, sh.x));
  float r1 = lrelu(fmaf(sc.y, v.y, sh.y));
  float r2 = lrelu(fmaf(sc.z, v.z, sh.z));
  float r3 = lrelu(fmaf(sc.w, v.w, sh.w));
  uint2 u;
  u.x = (unsigned)f2bf(r0) | ((unsigned)f2bf(r1) << 16);
  u.y = (unsigned)f2bf(r2) | ((unsigned)f2bf(r3) << 16);
  ((uint2*)h3)[q] = u;
}

// ---- conv2 as single-stage MFMA: per block (b, lq): M=64 l, N=64 f, K=128 ----
__global__ __launch_bounds__(256) void k_conv2(const unsigned short* __restrict__ h3,
                                               const unsigned short* __restrict__ wt2,
                                               const float* __restrict__ cb2,
                                               float* __restrict__ y4){
  __shared__ char smem[32768];   // A [64][128]bf16 16KB, B [64][128]bf16 16KB
  int blk = blockIdx.x;          // 256 = 64b * 4lq
  int b = blk >> 2, lq = blk & 3;
  int l0 = lq << 6;
  int tid = threadIdx.x;
  int w = tid >> 6, lane = tid & 63;
  int wm = w >> 1, wn = w & 1;
  #pragma unroll
  for (int i = 0; i < 4; i++){
    int r = (w << 4) + (i << 2) + (lane >> 4);
    int sw = (((lane & 15) ^ (r & 7)) << 3);
    gl16(h3 + (size_t)((b << 8) + l0 + r) * 128 + sw, smem + (w << 12) + (i << 10));
    gl16(wt2 + (size_t)r * 128 + sw, smem + 16384 + (w << 12) + (i << 10));
  }
  __syncthreads();
  f32x4 acc[2][2] = {};
  int m0 = (wm << 5) + (lane & 15);
  int n0 = (wn << 5) + (lane & 15);
  int kg = lane >> 4;
  const char* Ab = smem;
  const char* Bb = smem + 16384;
  #pragma unroll
  for (int ks = 0; ks < 4; ks++){
    int kb = kg + (ks << 2);
    short8 a0 = *(const short8*)(Ab + (m0 << 8)        + ((kb ^ (m0 & 7)) << 4));
    short8 a1 = *(const short8*)(Ab + ((m0 + 16) << 8) + ((kb ^ (m0 & 7)) << 4));
    short8 b0 = *(const short8*)(Bb + (n0 << 8)        + ((kb ^ (n0 & 7)) << 4));
    short8 b1 = *(const short8*)(Bb + ((n0 + 16) << 8) + ((kb ^ (n0 & 7)) << 4));
    acc[0][0] = __builtin_amdgcn_mfma_f32_16x16x32_bf16(a0, b0, acc[0][0], 0, 0, 0);
    acc[0][1] = __builtin_amdgcn_mfma_f32_16x16x32_bf16(a0, b1, acc[0][1], 0, 0, 0);
    acc[1][0] = __builtin_amdgcn_mfma_f32_16x16x32_bf16(a1, b0, acc[1][0], 0, 0, 0);
    acc[1][1] = __builtin_amdgcn_mfma_f32_16x16x32_bf16(a1, b1, acc[1][1], 0, 0, 0);
  }
  int rowb = l0 + (wm << 5) + ((lane >> 4) << 2);
  #pragma unroll
  for (int mi = 0; mi < 2; mi++){
    #pragma unroll
    for (int ni = 0; ni < 2; ni++){
      int f = n0 + (ni << 4);
      float bias = cb2[f];
      #pragma unroll
      for (int r = 0; r < 4; r++){
        y4[(size_t)((b << 8) + rowb + (mi << 4) + r) * 64 + f] = acc[mi][ni][r] + bias;
      }
    }
  }
}

// ---- per-f stats of y4 [row][64] ----
__global__ __launch_bounds__(256) void k_stats4(const float* __restrict__ y4,
                                                float* __restrict__ sum4,
                                                float* __restrict__ sq4){
  __shared__ float S[64], Q[64];
  int tid = threadIdx.x;
  if (tid < 64){ S[tid] = 0.f; Q[tid] = 0.f; }
  __syncthreads();
  int f = tid & 63, q4 = tid >> 6;
  float s = 0.f, q = 0.f;
  int r0 = blockIdx.x << 8;
  for (int i = 0; i < 64; i++){
    float v = y4[(size_t)(r0 + (i << 2) + q4) * 64 + f];
    s += v; q += v * v;
  }
  atomicAdd(&S[f], s); atomicAdd(&Q[f], q);
  __syncthreads();
  if (tid < 64){ atomicAdd(sum4 + tid, S[tid]); atomicAdd(sq4 + tid, Q[tid]); }
}

// ---- final: out = lrelu(bn4(y4)), layout already [b][l][f] ----
__global__ __launch_bounds__(256) void k_final(const float* __restrict__ y4,
                                               const float* __restrict__ sc4,
                                               const float* __restrict__ sh4,
                                               float* __restrict__ out){
  unsigned q = blockIdx.x * 256 + threadIdx.x;   // 262144 exact
  unsigned f0 = (q & 15) << 2;
  float4 v = ((const float4*)y4)[q];
  float4 sc = *(const float4*)(sc4 + f0);
  float4 sh = *(const float4*)(sh4 + f0);
  v.x = lrelu(fmaf(sc.x, v.x, sh.x));
  v.y = lrelu(fmaf(sc.y, v.y, sh.y));
  v.z = lrelu(fmaf(sc.z, v.z, sh.z));
  v.w = lrelu(fmaf(sc.w, v.w, sh.w));
  ((float4*)out)[q] = v;
}

extern "C" void kernel_launch(void* const* d_in, const int* in_sizes, int n_in,
                              void* d_out, int out_size, void* d_ws, size_t ws_size,
                              hipStream_t stream){
  const float* x    = (const float*)d_in[0];
  const float* W1   = (const float*)d_in[4];
  const float* b1   = (const float*)d_in[5];
  const float* g1   = (const float*)d_in[6];
  const float* be1  = (const float*)d_in[7];
  const float* W2   = (const float*)d_in[8];
  const float* b2   = (const float*)d_in[9];
  const float* g2   = (const float*)d_in[10];
  const float* be2  = (const float*)d_in[11];
  const float* cw1  = (const float*)d_in[12];
  const float* cb1  = (const float*)d_in[13];
  const float* cg1  = (const float*)d_in[14];
  const float* cbe1 = (const float*)d_in[15];
  const float* cw2  = (const float*)d_in[16];
  const float* cb2  = (const float*)d_in[17];
  const float* cg2  = (const float*)d_in[18];
  const float* cbe2 = (const float*)d_in[19];

  char* ws = (char*)d_ws;
  unsigned short* y2t = (unsigned short*)(ws + WS_Y2T);
  float* xa           = (float*)(ws + WS_XA);
  unsigned short* wt1 = (unsigned short*)(ws + WS_WT1);
  unsigned short* wt2 = (unsigned short*)(ws + WS_WT2);
  float* y3           = (float*)(ws + WS_Y3);
  unsigned short* h3  = (unsigned short*)(ws + WS_H3);
  float* y4           = (float*)(ws + WS_Y4);
  float* st           = (float*)(ws + WS_ST);

  if (ws_size < WS_ST + ST_COUNT * 4) return;

  hipMemsetAsync(st, 0, ST_COUNT * 4, stream);
  k_zpad  <<<64, 256, 0, stream>>>(y2t);
  k_wt    <<<416, 256, 0, stream>>>(cw1, cw2, wt1, wt2);
  k_gcn1  <<<1600, 256, 0, stream>>>(x, xa, st + ST_S9);
  k_bn1   <<<1, 64, 0, stream>>>(st + ST_S9, W1, b1, g1, be1, st + ST_S1, st + ST_T1);
  k_gcn2  <<<1600, 256, 0, stream>>>(xa, W1, st + ST_S1, st + ST_T1, W2, b2, y2t);
  k_stats2<<<1024, 256, 0, stream>>>(y2t, st + ST_SUM2, st + ST_SQ2);
  k_bnp   <<<1, 64, 0, stream>>>(st + ST_SUM2, st + ST_SQ2, g2, be2,
                                 st + ST_SC2, st + ST_SH2, 1.f / (float)NN_);
  k_bnapp2<<<2048, 256, 0, stream>>>(y2t, st + ST_SC2, st + ST_SH2);
  k_conv1 <<<512, 256, 0, stream>>>(y2t, wt1, cb1, y3);
  k_stats3<<<64, 256, 0, stream>>>(y3, st + ST_SUM3, st + ST_SQ3);
  k_bnp   <<<1, 128, 0, stream>>>(st + ST_SUM3, st + ST_SQ3, cg1, cbe1,
                                  st + ST_SC3, st + ST_SH3, 1.f / (float)MM_);
  k_h3    <<<2048, 256, 0, stream>>>(y3, st + ST_SC3, st + ST_SH3, h3);
  k_conv2 <<<256, 256, 0, stream>>>(h3, wt2, cb2, y4);
  k_stats4<<<64, 256, 0, stream>>>(y4, st + ST_SUM4, st + ST_SQ4);
  k_bnp   <<<1, 64, 0, stream>>>(st + ST_SUM4, st + ST_SQ4, cg2, cbe2,
                                 st + ST_SC4, st + ST_SH4, 1.f / (float)MM_);
  k_final <<<1024, 256, 0, stream>>>(y4, st + ST_SC4, st + ST_SH4, (float*)d_out);
}

// Round 3
// 192.909 us; speedup vs baseline: 6.5790x; 1.3214x over previous
//
#include <hip/hip_runtime.h>
#include <stdint.h>

#define B_ 64
#define F2_ 256
#define J_ 25
#define FILT_ 64
#define C1_ 1600   // J*FILT
#define O1_ 128
#define NN_ 409600 // B*F*J
#define MM_ 16384  // B*F
#define EPSV 1e-5f

typedef short short8 __attribute__((ext_vector_type(8)));
typedef float f32x4 __attribute__((ext_vector_type(4)));

// ---- workspace layout (bytes) ----
// y2t: bf16 [64][258][1600]  (rows 0 and 257 per batch are zero pads)
static const size_t WS_Y2T  = 0;                       // 52,838,400
static const size_t WS_XA   = 52838400;                // f32 [NN][3] 4,915,200
static const size_t WS_WT1  = 57753600;                // bf16 [3][128][1600] 1,228,800
static const size_t WS_WT2  = 58982400;                // bf16 [64][128] 16,384
static const size_t WS_WT2G = 58998784;                // bf16 [64][64] 8,192
static const size_t WS_Y3   = 59006976;                // f32 [64][256][128] 8,388,608
static const size_t WS_H3   = 67395584;                // bf16 [64][256][128] 4,194,304
static const size_t WS_Y4   = 71589888;                // f32 [64][256][64] 4,194,304
static const size_t WS_ST   = 75784192;                // f32 stats block
// stats block float offsets
#define ST_S9    0
#define ST_SUM2  16
#define ST_SQ2   80
#define ST_SUM3  144
#define ST_SQ3   272
#define ST_SUM4  400
#define ST_SQ4   464
#define ST_S1    528
#define ST_T1    592
#define ST_SC2   656
#define ST_SH2   720
#define ST_SC3   784
#define ST_SH3   912
#define ST_SC4   1040
#define ST_SH4   1104
#define ST_COUNT 1168

__device__ __forceinline__ float bf2f(unsigned int u){
  return __uint_as_float(u << 16);
}
__device__ __forceinline__ unsigned short f2bf(float f){
  unsigned int u = __float_as_uint(f);
  u += 0x7fffu + ((u >> 16) & 1u);   // RNE
  return (unsigned short)(u >> 16);
}
__device__ __forceinline__ float lrelu(float x){ return fmaxf(x, 0.2f * x); }
__device__ __forceinline__ float wsum(float v){
  #pragma unroll
  for (int off = 32; off > 0; off >>= 1) v += __shfl_down(v, off, 64);
  return v;
}

typedef __attribute__((address_space(3))) unsigned int lds_uint_t;
typedef __attribute__((address_space(1))) const unsigned int glob_uint_t;
__device__ __forceinline__ void gl16(const void* g, void* l){
  __builtin_amdgcn_global_load_lds((glob_uint_t*)g, (lds_uint_t*)l, 16, 0, 0);
}

// ---- zero the pad rows of y2t (rows 0 and 257 of each batch) ----
__global__ __launch_bounds__(256) void k_zpad(unsigned short* __restrict__ y2t){
  int b = blockIdx.x, tid = threadIdx.x;
  if (tid < 200){
    uint4 z = make_uint4(0,0,0,0);
    ((uint4*)(y2t + (size_t)b * 412800))[tid] = z;
    ((uint4*)(y2t + (size_t)b * 412800 + 257 * 1600))[tid] = z;
  }
}

// ---- weight transforms ----
// wt1[k][o][c] = cw1[o][c][k]; wt2[f][c] = cw2[f][c]; wt2g[f][cc] = W2[cc][f]
__global__ __launch_bounds__(256) void k_wt(const float* __restrict__ cw1,
                                            const float* __restrict__ W2,
                                            const float* __restrict__ cw2,
                                            unsigned short* __restrict__ wt1,
                                            unsigned short* __restrict__ wt2,
                                            unsigned short* __restrict__ wt2g){
  int blk = blockIdx.x;
  if (blk < 384){
    int k = blk >> 7, o = blk & 127;
    for (int c = threadIdx.x; c < 1600; c += 256)
      wt1[(size_t)(k * 128 + o) * 1600 + c] = f2bf(cw1[(size_t)(o * 1600 + c) * 3 + k]);
  } else if (blk < 416){
    int idx = ((blk - 384) << 8) + threadIdx.x;   // 8192
    wt2[idx] = f2bf(cw2[idx]);
  } else {
    int idx = ((blk - 416) << 8) + threadIdx.x;   // 4096
    int f = idx >> 6, cc = idx & 63;
    wt2g[idx] = f2bf(W2[cc * 64 + f]);
  }
}

// ---- GCN1 aggregate + 9-scalar moments ----
__global__ __launch_bounds__(256) void k_gcn1(const float* __restrict__ x,
                                              float* __restrict__ xa,
                                              float* __restrict__ S9){
  int n = blockIdx.x * 256 + threadIdx.x;
  int j = n % J_;
  float dj  = (j == 0 || j == J_-1) ? 2.f : 3.f;
  float rdj = rsqrtf(dj);
  const float* xp = x + (size_t)n * 3;
  float wg = 1.f / dj;
  float a0 = xp[0]*wg, a1 = xp[1]*wg, a2 = xp[2]*wg;
  if (j > 0){
    float dm = (j == 1) ? 2.f : 3.f;  float w = rdj * rsqrtf(dm);
    a0 += xp[-3]*w; a1 += xp[-2]*w; a2 += xp[-1]*w;
  }
  if (j < J_-1){
    float dp = (j == J_-2) ? 2.f : 3.f;  float w = rdj * rsqrtf(dp);
    a0 += xp[3]*w; a1 += xp[4]*w; a2 += xp[5]*w;
  }
  float* xo = xa + (size_t)n * 3;
  xo[0] = a0; xo[1] = a1; xo[2] = a2;
  float p[9] = {a0, a1, a2, a0*a0, a0*a1, a0*a2, a1*a1, a1*a2, a2*a2};
  __shared__ float tmp[9][4];
  int wv = threadIdx.x >> 6, ln = threadIdx.x & 63;
  #pragma unroll
  for (int k = 0; k < 9; k++){ float s = wsum(p[k]); if (ln == 0) tmp[k][wv] = s; }
  __syncthreads();
  if (threadIdx.x < 9){
    int k = threadIdx.x;
    atomicAdd(S9 + k, tmp[k][0] + tmp[k][1] + tmp[k][2] + tmp[k][3]);
  }
}

__global__ void k_bn1(const float* __restrict__ S9, const float* __restrict__ W1,
                      const float* __restrict__ b1, const float* __restrict__ g1,
                      const float* __restrict__ be1,
                      float* __restrict__ s1, float* __restrict__ t1){
  int c = threadIdx.x;
  float inv = 1.f / (float)NN_;
  float m0 = S9[0]*inv, m1 = S9[1]*inv, m2 = S9[2]*inv;
  float C00 = S9[3]*inv - m0*m0, C01 = S9[4]*inv - m0*m1, C02 = S9[5]*inv - m0*m2;
  float C11 = S9[6]*inv - m1*m1, C12 = S9[7]*inv - m1*m2, C22 = S9[8]*inv - m2*m2;
  float w0 = W1[c], w1 = W1[64+c], w2 = W1[128+c];
  float mean = m0*w0 + m1*w1 + m2*w2 + b1[c];
  float var  = w0*w0*C00 + w1*w1*C11 + w2*w2*C22
             + 2.f*(w0*w1*C01 + w0*w2*C02 + w1*w2*C12);
  float s = g1[c] * rsqrtf(var + EPSV);
  s1[c] = s;
  t1[c] = be1[c] - s*mean + s*b1[c];
}

// ---- GCN2 via MFMA: h1 register-ring + j-stencil agg + 64x64 GEMM, fused BN2 stats ----
#define H1SLICE(ph, js) do { \
  int js_ = (js); \
  _Pragma("unroll") \
  for (int i_ = 0; i_ < 16; i_++){ \
    const float* xp_ = xas + ((size_t)(wl0 + i_) * 25 + js_) * 3; \
    h[ph][i_] = lrelu(fmaf(sS, fmaf(xp_[0], w0c, fmaf(xp_[1], w1c, xp_[2]*w2c)), tT)); \
  } } while(0)

#define AGGW(pm, pc, pp) do { \
  _Pragma("unroll") \
  for (int i_ = 0; i_ < 16; i_++){ \
    float a_ = wgm*h[pm][i_] + wgs*h[pc][i_] + wgp*h[pp][i_]; \
    int row_ = wl0 + i_; \
    *(unsigned short*)(As + row_*128 + ((((lane>>3)) ^ (row_&7))<<4) + ((lane&7)<<1)) = f2bf(a_); \
  } } while(0)

__global__ __launch_bounds__(256) void k_gcn2m(const float* __restrict__ xa,
                                               const float* __restrict__ W1,
                                               const float* __restrict__ s1,
                                               const float* __restrict__ t1,
                                               const float* __restrict__ b2,
                                               const unsigned short* __restrict__ wt2g,
                                               unsigned short* __restrict__ y2t,
                                               float* __restrict__ sum2,
                                               float* __restrict__ sq2){
  __shared__ float xas[4800];          // [l][j][d], contiguous copy
  __shared__ float prm[384];           // W1(192) s1(64) t1(64) b2(64)
  __shared__ char As[8192];            // agg tile [64 l][64 cc] bf16, swizzled
  __shared__ char Bs[8192];            // wt2g tile [64 f][64 cc] bf16, swizzled
  int blk = blockIdx.x;                // 512 = ((b*4)+lq)*2 + jh
  int jh = blk & 1;
  int lq = (blk >> 1) & 3;
  int b  = blk >> 3;
  int l0 = lq << 6;
  int tid = threadIdx.x;
  int w = tid >> 6, lane = tid & 63;

  // stage xas (contiguous 4800 floats)
  const float* xsrc = xa + (size_t)(b * 256 + l0) * 75;
  #pragma unroll
  for (int i = 0; i < 5; i++){
    int idx = tid + (i << 8);
    if (idx < 1200) ((float4*)xas)[idx] = ((const float4*)xsrc)[idx];
  }
  // stage prm
  prm[tid] = (tid < 192) ? W1[tid] : s1[tid - 192];
  if (tid < 128) prm[256 + tid] = (tid < 64) ? t1[tid] : b2[tid - 64];
  // stage Bs via global_load_lds with pre-swizzled source
  #pragma unroll
  for (int i = 0; i < 2; i++){
    int r = (w << 4) + (i << 3) + (lane >> 3);
    int cblk = lane & 7;
    gl16(wt2g + (size_t)r * 64 + (((cblk ^ (r & 7))) << 3),
         Bs + (w << 11) + (i << 10));
  }
  __syncthreads();

  // per-thread hoisted coefficients (ch = lane)
  float w0c = prm[lane], w1c = prm[64 + lane], w2c = prm[128 + lane];
  float sS = prm[192 + lane], tT = prm[256 + lane];
  int wm = w >> 1, wn = w & 1;
  int m0 = (wm << 5) + (lane & 15);
  int n0 = (wn << 5) + (lane & 15);
  int kg = lane >> 4;
  float bias0 = prm[320 + n0], bias1 = prm[320 + n0 + 16];
  int wl0 = w << 4;

  float h[3][16];
  int J0 = jh ? 12 : 0;      // J0 % 3 == 0 in both cases -> static ring phases
  int NJ = jh ? 13 : 12;
  #pragma unroll
  for (int i = 0; i < 16; i++) h[2][i] = 0.f;
  H1SLICE(0, J0);
  if (J0 > 0) H1SLICE(2, J0 - 1);

  float ss0 = 0.f, ss1 = 0.f, qq0 = 0.f, qq1 = 0.f;

  #pragma unroll
  for (int jj = 0; jj < 13; jj++){
    if (jj >= NJ) break;
    int j = J0 + jj;
    // compute slice j+1 into phase (jj+1)%3
    if (j + 1 <= 24){
      switch ((jj + 1) % 3){
        case 0: H1SLICE(0, j + 1); break;
        case 1: H1SLICE(1, j + 1); break;
        case 2: H1SLICE(2, j + 1); break;
      }
    }
    float dj  = (j == 0 || j == 24) ? 2.f : 3.f;
    float rdj = rsqrtf(dj);
    float wgs = 1.f / dj;
    float wgm = (j > 0)  ? rdj * rsqrtf((j == 1)  ? 2.f : 3.f) : 0.f;
    float wgp = (j < 24) ? rdj * rsqrtf((j == 23) ? 2.f : 3.f) : 0.f;
    // aggregate into As (phases: j-1=(jj+2)%3, j=jj%3, j+1=(jj+1)%3)
    switch (jj % 3){
      case 0: AGGW(2, 0, 1); break;
      case 1: AGGW(0, 1, 2); break;
      case 2: AGGW(1, 2, 0); break;
    }
    __syncthreads();
    f32x4 acc[2][2] = {};
    #pragma unroll
    for (int ks = 0; ks < 2; ks++){
      int kb = kg + (ks << 2);
      short8 a0 = *(const short8*)(As + (m0 << 7)        + ((kb ^ (m0 & 7)) << 4));
      short8 a1 = *(const short8*)(As + ((m0 + 16) << 7) + ((kb ^ (m0 & 7)) << 4));
      short8 b0 = *(const short8*)(Bs + (n0 << 7)        + ((kb ^ (n0 & 7)) << 4));
      short8 b1 = *(const short8*)(Bs + ((n0 + 16) << 7) + ((kb ^ (n0 & 7)) << 4));
      acc[0][0] = __builtin_amdgcn_mfma_f32_16x16x32_bf16(a0, b0, acc[0][0], 0, 0, 0);
      acc[0][1] = __builtin_amdgcn_mfma_f32_16x16x32_bf16(a0, b1, acc[0][1], 0, 0, 0);
      acc[1][0] = __builtin_amdgcn_mfma_f32_16x16x32_bf16(a1, b0, acc[1][0], 0, 0, 0);
      acc[1][1] = __builtin_amdgcn_mfma_f32_16x16x32_bf16(a1, b1, acc[1][1], 0, 0, 0);
    }
    __syncthreads();   // As reusable next j
    // epilogue: bias, stats partials, bf16 store
    int rowb = (wm << 5) + ((lane >> 4) << 2);
    #pragma unroll
    for (int mi = 0; mi < 2; mi++){
      #pragma unroll
      for (int ni = 0; ni < 2; ni++){
        float bias = ni ? bias1 : bias0;
        int f = n0 + (ni << 4);
        #pragma unroll
        for (int r = 0; r < 4; r++){
          float v = acc[mi][ni][r] + bias;
          if (ni){ ss1 += v; qq1 += v * v; } else { ss0 += v; qq0 += v * v; }
          int rl = rowb + (mi << 4) + r;
          y2t[(size_t)(b * 258 + l0 + rl + 1) * 1600 + j * 64 + f] = f2bf(v);
        }
      }
    }
  }
  // stats reduce across the 4 kg groups
  ss0 += __shfl_xor(ss0, 16, 64); ss0 += __shfl_xor(ss0, 32, 64);
  ss1 += __shfl_xor(ss1, 16, 64); ss1 += __shfl_xor(ss1, 32, 64);
  qq0 += __shfl_xor(qq0, 16, 64); qq0 += __shfl_xor(qq0, 32, 64);
  qq1 += __shfl_xor(qq1, 16, 64); qq1 += __shfl_xor(qq1, 32, 64);
  if ((lane >> 4) == 0){
    atomicAdd(sum2 + n0, ss0);      atomicAdd(sq2 + n0, qq0);
    atomicAdd(sum2 + n0 + 16, ss1); atomicAdd(sq2 + n0 + 16, qq1);
  }
}

__global__ void k_bnp(const float* __restrict__ sum, const float* __restrict__ sq,
                      const float* __restrict__ g, const float* __restrict__ be,
                      float* __restrict__ sc, float* __restrict__ sh, float inv){
  int c = threadIdx.x;
  float mean = sum[c] * inv;
  float var  = sq[c] * inv - mean * mean;
  float s = g[c] * rsqrtf(var + EPSV);
  sc[c] = s; sh[c] = be[c] - s * mean;
}

// ---- apply BN2+lrelu in place on y2t data rows only (pads stay zero) ----
__global__ __launch_bounds__(256) void k_bnapp2(unsigned short* __restrict__ y2t,
                                                const float* __restrict__ sc2,
                                                const float* __restrict__ sh2){
  for (unsigned idx = blockIdx.x * 256 + threadIdx.x; idx < 3276800u; idx += 524288u){
    unsigned b = idx / 51200u;
    unsigned rem = idx - b * 51200u;
    unsigned l = rem / 200u;
    unsigned cg = rem - l * 200u;
    uint4* p = (uint4*)y2t + ((size_t)b * 258 + l + 1) * 200 + cg;
    unsigned f0 = (cg << 3) & 63u;
    float4 sa = *(const float4*)(sc2 + f0);
    float4 sb = *(const float4*)(sc2 + f0 + 4);
    float4 ha = *(const float4*)(sh2 + f0);
    float4 hb = *(const float4*)(sh2 + f0 + 4);
    float scs[8] = {sa.x,sa.y,sa.z,sa.w,sb.x,sb.y,sb.z,sb.w};
    float shs[8] = {ha.x,ha.y,ha.z,ha.w,hb.x,hb.y,hb.z,hb.w};
    uint4 v = *p;
    unsigned vv[4] = {v.x,v.y,v.z,v.w};
    unsigned r[4];
    #pragma unroll
    for (int i = 0; i < 4; i++){
      float lo = bf2f(vv[i] & 0xffffu);
      float hi = bf2f(vv[i] >> 16);
      lo = lrelu(fmaf(scs[2*i],   lo, shs[2*i]));
      hi = lrelu(fmaf(scs[2*i+1], hi, shs[2*i+1]));
      r[i] = (unsigned)f2bf(lo) | (((unsigned)f2bf(hi)) << 16);
    }
    *p = make_uint4(r[0],r[1],r[2],r[3]);
  }
}

// ---- conv1 as MFMA GEMM + fused stats3 ----
#define NT_ 75
__global__ __launch_bounds__(256) void k_conv1(const unsigned short* __restrict__ y2t,
                                               const unsigned short* __restrict__ wt1,
                                               const float* __restrict__ cb1,
                                               float* __restrict__ y3,
                                               float* __restrict__ sum3,
                                               float* __restrict__ sq3){
  __shared__ char smem[32768];
  int blk = blockIdx.x;          // 512 = 64b * 4lq * 2og
  int b  = blk >> 3;
  int lq = (blk >> 1) & 3;
  int og = blk & 1;
  int l0 = lq << 6;
  int tid = threadIdx.x;
  int w = tid >> 6, lane = tid & 63;
  int wm = w >> 1, wn = w & 1;
  const unsigned short* y2b = y2t + (size_t)b * 412800;
  const unsigned short* wtb = wt1 + (size_t)og * 64 * 1600;

  int rs = (w << 4) + (lane >> 3);
  int cblk = lane & 7;
  int m0 = (wm << 5) + (lane & 15);
  int n0 = (wn << 5) + (lane & 15);
  int kg = lane >> 4;

  f32x4 acc[2][2] = {};

  auto stage = [&](int t, int buf){
    int k = t / 25;
    int cc = (t - k * 25) << 6;
    const unsigned short* wk = wtb + (size_t)k * 204800;
    #pragma unroll
    for (int i = 0; i < 2; i++){
      int r = rs + (i << 3);
      int sw = (cblk ^ (r & 7)) << 3;
      gl16(y2b + (size_t)(l0 + r + k) * 1600 + cc + sw,
           smem + buf * 16384 + (w << 11) + (i << 10));
      gl16(wk + (size_t)r * 1600 + cc + sw,
           smem + buf * 16384 + 8192 + (w << 11) + (i << 10));
    }
  };

  stage(0, 0);
  __syncthreads();
  #pragma unroll 2
  for (int t = 0; t < NT_; ++t){
    int buf = t & 1;
    if (t + 1 < NT_) stage(t + 1, buf ^ 1);
    const char* Ab = smem + buf * 16384;
    const char* Bb = Ab + 8192;
    #pragma unroll
    for (int ks = 0; ks < 2; ks++){
      int kb = kg + (ks << 2);
      short8 a0 = *(const short8*)(Ab + (m0 << 7)        + ((kb ^ (m0 & 7)) << 4));
      short8 a1 = *(const short8*)(Ab + ((m0 + 16) << 7) + ((kb ^ (m0 & 7)) << 4));
      short8 b0 = *(const short8*)(Bb + (n0 << 7)        + ((kb ^ (n0 & 7)) << 4));
      short8 b1 = *(const short8*)(Bb + ((n0 + 16) << 7) + ((kb ^ (n0 & 7)) << 4));
      acc[0][0] = __builtin_amdgcn_mfma_f32_16x16x32_bf16(a0, b0, acc[0][0], 0, 0, 0);
      acc[0][1] = __builtin_amdgcn_mfma_f32_16x16x32_bf16(a0, b1, acc[0][1], 0, 0, 0);
      acc[1][0] = __builtin_amdgcn_mfma_f32_16x16x32_bf16(a1, b0, acc[1][0], 0, 0, 0);
      acc[1][1] = __builtin_amdgcn_mfma_f32_16x16x32_bf16(a1, b1, acc[1][1], 0, 0, 0);
    }
    __syncthreads();
  }

  int colb = (og << 6) + n0;
  int rowb = l0 + (wm << 5) + ((lane >> 4) << 2);
  float ss0 = 0.f, ss1 = 0.f, qq0 = 0.f, qq1 = 0.f;
  #pragma unroll
  for (int mi = 0; mi < 2; mi++){
    #pragma unroll
    for (int ni = 0; ni < 2; ni++){
      int col = colb + (ni << 4);
      float bias = cb1[col];
      #pragma unroll
      for (int r = 0; r < 4; r++){
        float v = acc[mi][ni][r] + bias;
        if (ni){ ss1 += v; qq1 += v * v; } else { ss0 += v; qq0 += v * v; }
        y3[(size_t)((b << 8) + rowb + (mi << 4) + r) * 128 + col] = v;
      }
    }
  }
  ss0 += __shfl_xor(ss0, 16, 64); ss0 += __shfl_xor(ss0, 32, 64);
  ss1 += __shfl_xor(ss1, 16, 64); ss1 += __shfl_xor(ss1, 32, 64);
  qq0 += __shfl_xor(qq0, 16, 64); qq0 += __shfl_xor(qq0, 32, 64);
  qq1 += __shfl_xor(qq1, 16, 64); qq1 += __shfl_xor(qq1, 32, 64);
  if ((lane >> 4) == 0){
    atomicAdd(sum3 + colb, ss0);      atomicAdd(sq3 + colb, qq0);
    atomicAdd(sum3 + colb + 16, ss1); atomicAdd(sq3 + colb + 16, qq1);
  }
}

// ---- h3 = bf16(lrelu(bn3(y3))) ----
__global__ __launch_bounds__(256) void k_h3(const float* __restrict__ y3,
                                            const float* __restrict__ sc3,
                                            const float* __restrict__ sh3,
                                            unsigned short* __restrict__ h3){
  unsigned q = blockIdx.x * 256 + threadIdx.x;
  unsigned o0 = (q & 31) << 2;
  float4 v = ((const float4*)y3)[q];
  float4 sc = *(const float4*)(sc3 + o0);
  float4 sh = *(const float4*)(sh3 + o0);
  float r0 = lrelu(fmaf(sc.x, v.x, sh.x));
  float r1 = lrelu(fmaf(sc.y, v.y, sh.y));
  float r2 = lrelu(fmaf(sc.z, v.z, sh.z));
  float r3 = lrelu(fmaf(sc.w, v.w, sh.w));
  uint2 u;
  u.x = (unsigned)f2bf(r0) | ((unsigned)f2bf(r1) << 16);
  u.y = (unsigned)f2bf(r2) | ((unsigned)f2bf(r3) << 16);
  ((uint2*)h3)[q] = u;
}

// ---- conv2 MFMA + fused stats4 ----
__global__ __launch_bounds__(256) void k_conv2(const unsigned short* __restrict__ h3,
                                               const unsigned short* __restrict__ wt2,
                                               const float* __restrict__ cb2,
                                               float* __restrict__ y4,
                                               float* __restrict__ sum4,
                                               float* __restrict__ sq4){
  __shared__ char smem[32768];
  int blk = blockIdx.x;          // 256 = 64b * 4lq
  int b = blk >> 2, lq = blk & 3;
  int l0 = lq << 6;
  int tid = threadIdx.x;
  int w = tid >> 6, lane = tid & 63;
  int wm = w >> 1, wn = w & 1;
  #pragma unroll
  for (int i = 0; i < 4; i++){
    int r = (w << 4) + (i << 2) + (lane >> 4);
    int sw = (((lane & 15) ^ (r & 7)) << 3);
    gl16(h3 + (size_t)((b << 8) + l0 + r) * 128 + sw, smem + (w << 12) + (i << 10));
    gl16(wt2 + (size_t)r * 128 + sw, smem + 16384 + (w << 12) + (i << 10));
  }
  __syncthreads();
  f32x4 acc[2][2] = {};
  int m0 = (wm << 5) + (lane & 15);
  int n0 = (wn << 5) + (lane & 15);
  int kg = lane >> 4;
  const char* Ab = smem;
  const char* Bb = smem + 16384;
  #pragma unroll
  for (int ks = 0; ks < 4; ks++){
    int kb = kg + (ks << 2);
    short8 a0 = *(const short8*)(Ab + (m0 << 8)        + ((kb ^ (m0 & 7)) << 4));
    short8 a1 = *(const short8*)(Ab + ((m0 + 16) << 8) + ((kb ^ (m0 & 7)) << 4));
    short8 b0 = *(const short8*)(Bb + (n0 << 8)        + ((kb ^ (n0 & 7)) << 4));
    short8 b1 = *(const short8*)(Bb + ((n0 + 16) << 8) + ((kb ^ (n0 & 7)) << 4));
    acc[0][0] = __builtin_amdgcn_mfma_f32_16x16x32_bf16(a0, b0, acc[0][0], 0, 0, 0);
    acc[0][1] = __builtin_amdgcn_mfma_f32_16x16x32_bf16(a0, b1, acc[0][1], 0, 0, 0);
    acc[1][0] = __builtin_amdgcn_mfma_f32_16x16x32_bf16(a1, b0, acc[1][0], 0, 0, 0);
    acc[1][1] = __builtin_amdgcn_mfma_f32_16x16x32_bf16(a1, b1, acc[1][1], 0, 0, 0);
  }
  int rowb = l0 + (wm << 5) + ((lane >> 4) << 2);
  float ss0 = 0.f, ss1 = 0.f, qq0 = 0.f, qq1 = 0.f;
  #pragma unroll
  for (int mi = 0; mi < 2; mi++){
    #pragma unroll
    for (int ni = 0; ni < 2; ni++){
      int f = n0 + (ni << 4);
      float bias = cb2[f];
      #pragma unroll
      for (int r = 0; r < 4; r++){
        float v = acc[mi][ni][r] + bias;
        if (ni){ ss1 += v; qq1 += v * v; } else { ss0 += v; qq0 += v * v; }
        y4[(size_t)((b << 8) + rowb + (mi << 4) + r) * 64 + f] = v;
      }
    }
  }
  ss0 += __shfl_xor(ss0, 16, 64); ss0 += __shfl_xor(ss0, 32, 64);
  ss1 += __shfl_xor(ss1, 16, 64); ss1 += __shfl_xor(ss1, 32, 64);
  qq0 += __shfl_xor(qq0, 16, 64); qq0 += __shfl_xor(qq0, 32, 64);
  qq1 += __shfl_xor(qq1, 16, 64); qq1 += __shfl_xor(qq1, 32, 64);
  if ((lane >> 4) == 0){
    atomicAdd(sum4 + n0, ss0);      atomicAdd(sq4 + n0, qq0);
    atomicAdd(sum4 + n0 + 16, ss1); atomicAdd(sq4 + n0 + 16, qq1);
  }
}

// ---- final: out = lrelu(bn4(y4)) ----
__global__ __launch_bounds__(256) void k_final(const float* __restrict__ y4,
                                               const float* __restrict__ sc4,
                                               const float* __restrict__ sh4,
                                               float* __restrict__ out){
  unsigned q = blockIdx.x * 256 + threadIdx.x;
  unsigned f0 = (q & 15) << 2;
  float4 v = ((const float4*)y4)[q];
  float4 sc = *(const float4*)(sc4 + f0);
  float4 sh = *(const float4*)(sh4 + f0);
  v.x = lrelu(fmaf(sc.x, v.x, sh.x));
  v.y = lrelu(fmaf(sc.y, v.y, sh.y));
  v.z = lrelu(fmaf(sc.z, v.z, sh.z));
  v.w = lrelu(fmaf(sc.w, v.w, sh.w));
  ((float4*)out)[q] = v;
}

extern "C" void kernel_launch(void* const* d_in, const int* in_sizes, int n_in,
                              void* d_out, int out_size, void* d_ws, size_t ws_size,
                              hipStream_t stream){
  const float* x    = (const float*)d_in[0];
  const float* W1   = (const float*)d_in[4];
  const float* b1   = (const float*)d_in[5];
  const float* g1   = (const float*)d_in[6];
  const float* be1  = (const float*)d_in[7];
  const float* W2   = (const float*)d_in[8];
  const float* b2   = (const float*)d_in[9];
  const float* g2   = (const float*)d_in[10];
  const float* be2  = (const float*)d_in[11];
  const float* cw1  = (const float*)d_in[12];
  const float* cb1  = (const float*)d_in[13];
  const float* cg1  = (const float*)d_in[14];
  const float* cbe1 = (const float*)d_in[15];
  const float* cw2  = (const float*)d_in[16];
  const float* cb2  = (const float*)d_in[17];
  const float* cg2  = (const float*)d_in[18];
  const float* cbe2 = (const float*)d_in[19];

  char* ws = (char*)d_ws;
  unsigned short* y2t  = (unsigned short*)(ws + WS_Y2T);
  float* xa            = (float*)(ws + WS_XA);
  unsigned short* wt1  = (unsigned short*)(ws + WS_WT1);
  unsigned short* wt2  = (unsigned short*)(ws + WS_WT2);
  unsigned short* wt2g = (unsigned short*)(ws + WS_WT2G);
  float* y3            = (float*)(ws + WS_Y3);
  unsigned short* h3   = (unsigned short*)(ws + WS_H3);
  float* y4            = (float*)(ws + WS_Y4);
  float* st            = (float*)(ws + WS_ST);

  if (ws_size < WS_ST + ST_COUNT * 4) return;

  hipMemsetAsync(st, 0, ST_COUNT * 4, stream);
  k_zpad  <<<64, 256, 0, stream>>>(y2t);
  k_wt    <<<432, 256, 0, stream>>>(cw1, W2, cw2, wt1, wt2, wt2g);
  k_gcn1  <<<1600, 256, 0, stream>>>(x, xa, st + ST_S9);
  k_bn1   <<<1, 64, 0, stream>>>(st + ST_S9, W1, b1, g1, be1, st + ST_S1, st + ST_T1);
  k_gcn2m <<<512, 256, 0, stream>>>(xa, W1, st + ST_S1, st + ST_T1, b2, wt2g,
                                    y2t, st + ST_SUM2, st + ST_SQ2);
  k_bnp   <<<1, 64, 0, stream>>>(st + ST_SUM2, st + ST_SQ2, g2, be2,
                                 st + ST_SC2, st + ST_SH2, 1.f / (float)NN_);
  k_bnapp2<<<2048, 256, 0, stream>>>(y2t, st + ST_SC2, st + ST_SH2);
  k_conv1 <<<512, 256, 0, stream>>>(y2t, wt1, cb1, y3, st + ST_SUM3, st + ST_SQ3);
  k_bnp   <<<1, 128, 0, stream>>>(st + ST_SUM3, st + ST_SQ3, cg1, cbe1,
                                  st + ST_SC3, st + ST_SH3, 1.f / (float)MM_);
  k_h3    <<<2048, 256, 0, stream>>>(y3, st + ST_SC3, st + ST_SH3, h3);
  k_conv2 <<<256, 256, 0, stream>>>(h3, wt2, cb2, y4, st + ST_SUM4, st + ST_SQ4);
  k_bnp   <<<1, 64, 0, stream>>>(st + ST_SUM4, st + ST_SQ4, cg2, cbe2,
                                 st + ST_SC4, st + ST_SH4, 1.f / (float)MM_);
  k_final <<<1024, 256, 0, stream>>>(y4, st + ST_SC4, st + ST_SH4, (float*)d_out);
}

// Round 4
// 177.918 us; speedup vs baseline: 7.1333x; 1.0843x over previous
//
#include <hip/hip_runtime.h>
#include <stdint.h>

#define B_ 64
#define F2_ 256
#define J_ 25
#define FILT_ 64
#define C1_ 1600   // J*FILT
#define O1_ 128
#define NN_ 409600 // B*F*J
#define MM_ 16384  // B*F
#define EPSV 1e-5f

typedef short short8 __attribute__((ext_vector_type(8)));
typedef float f32x4 __attribute__((ext_vector_type(4)));

// ---- workspace layout (bytes) ----
// y2t: bf16 [64][258][1600]  (rows 0 and 257 per batch are zero pads)
static const size_t WS_Y2T  = 0;                       // 52,838,400
static const size_t WS_XA   = 52838400;                // f32 [NN][3] 4,915,200
static const size_t WS_WT1  = 57753600;                // bf16 [3][128][1600] 1,228,800
static const size_t WS_WT2  = 58982400;                // bf16 [64][128] 16,384
static const size_t WS_WT2G = 58998784;                // bf16 [64][64] 8,192
static const size_t WS_Y3   = 59006976;                // f32 [64][256][128] 8,388,608
static const size_t WS_Y4   = 67395584;                // f32 [64][256][64] 4,194,304
static const size_t WS_ST   = 71589888;                // f32 stats block
// stats block float offsets
#define ST_S9    0
#define ST_SUM2  16
#define ST_SQ2   80
#define ST_SUM3  144
#define ST_SQ3   272
#define ST_SUM4  400
#define ST_SQ4   464
#define ST_S1    528
#define ST_T1    592
#define ST_SC2   656
#define ST_SH2   720
#define ST_SC3   784
#define ST_SH3   912
#define ST_SC4   1040
#define ST_SH4   1104
#define ST_COUNT 1168

__device__ __forceinline__ float bf2f(unsigned int u){
  return __uint_as_float(u << 16);
}
__device__ __forceinline__ unsigned short f2bf(float f){
  unsigned int u = __float_as_uint(f);
  u += 0x7fffu + ((u >> 16) & 1u);   // RNE
  return (unsigned short)(u >> 16);
}
__device__ __forceinline__ float lrelu(float x){ return fmaxf(x, 0.2f * x); }
__device__ __forceinline__ float wsum(float v){
  #pragma unroll
  for (int off = 32; off > 0; off >>= 1) v += __shfl_down(v, off, 64);
  return v;
}

typedef __attribute__((address_space(3))) unsigned int lds_uint_t;
typedef __attribute__((address_space(1))) const unsigned int glob_uint_t;
__device__ __forceinline__ void gl16(const void* g, void* l){
  __builtin_amdgcn_global_load_lds((glob_uint_t*)g, (lds_uint_t*)l, 16, 0, 0);
}

// ---- zero the pad rows of y2t (rows 0 and 257 of each batch) ----
__global__ __launch_bounds__(256) void k_zpad(unsigned short* __restrict__ y2t){
  int b = blockIdx.x, tid = threadIdx.x;
  if (tid < 200){
    uint4 z = make_uint4(0,0,0,0);
    ((uint4*)(y2t + (size_t)b * 412800))[tid] = z;
    ((uint4*)(y2t + (size_t)b * 412800 + 257 * 1600))[tid] = z;
  }
}

// ---- weight transforms ----
// wt1[k][o][c] = cw1[o][c][k]; wt2[f][c] = cw2[f][c]; wt2g[f][cc] = W2[cc][f]
__global__ __launch_bounds__(256) void k_wt(const float* __restrict__ cw1,
                                            const float* __restrict__ W2,
                                            const float* __restrict__ cw2,
                                            unsigned short* __restrict__ wt1,
                                            unsigned short* __restrict__ wt2,
                                            unsigned short* __restrict__ wt2g){
  int blk = blockIdx.x;
  if (blk < 384){
    int k = blk >> 7, o = blk & 127;
    for (int c = threadIdx.x; c < 1600; c += 256)
      wt1[(size_t)(k * 128 + o) * 1600 + c] = f2bf(cw1[(size_t)(o * 1600 + c) * 3 + k]);
  } else if (blk < 416){
    int idx = ((blk - 384) << 8) + threadIdx.x;   // 8192
    wt2[idx] = f2bf(cw2[idx]);
  } else {
    int idx = ((blk - 416) << 8) + threadIdx.x;   // 4096
    int f = idx >> 6, cc = idx & 63;
    wt2g[idx] = f2bf(W2[cc * 64 + f]);
  }
}

// ---- GCN1 aggregate + 9-scalar moments ----
__global__ __launch_bounds__(256) void k_gcn1(const float* __restrict__ x,
                                              float* __restrict__ xa,
                                              float* __restrict__ S9){
  int n = blockIdx.x * 256 + threadIdx.x;
  int j = n % J_;
  float dj  = (j == 0 || j == J_-1) ? 2.f : 3.f;
  float rdj = rsqrtf(dj);
  const float* xp = x + (size_t)n * 3;
  float wg = 1.f / dj;
  float a0 = xp[0]*wg, a1 = xp[1]*wg, a2 = xp[2]*wg;
  if (j > 0){
    float dm = (j == 1) ? 2.f : 3.f;  float w = rdj * rsqrtf(dm);
    a0 += xp[-3]*w; a1 += xp[-2]*w; a2 += xp[-1]*w;
  }
  if (j < J_-1){
    float dp = (j == J_-2) ? 2.f : 3.f;  float w = rdj * rsqrtf(dp);
    a0 += xp[3]*w; a1 += xp[4]*w; a2 += xp[5]*w;
  }
  float* xo = xa + (size_t)n * 3;
  xo[0] = a0; xo[1] = a1; xo[2] = a2;
  float p[9] = {a0, a1, a2, a0*a0, a0*a1, a0*a2, a1*a1, a1*a2, a2*a2};
  __shared__ float tmp[9][4];
  int wv = threadIdx.x >> 6, ln = threadIdx.x & 63;
  #pragma unroll
  for (int k = 0; k < 9; k++){ float s = wsum(p[k]); if (ln == 0) tmp[k][wv] = s; }
  __syncthreads();
  if (threadIdx.x < 9){
    int k = threadIdx.x;
    atomicAdd(S9 + k, tmp[k][0] + tmp[k][1] + tmp[k][2] + tmp[k][3]);
  }
}

__global__ void k_bn1(const float* __restrict__ S9, const float* __restrict__ W1,
                      const float* __restrict__ b1, const float* __restrict__ g1,
                      const float* __restrict__ be1,
                      float* __restrict__ s1, float* __restrict__ t1){
  int c = threadIdx.x;
  float inv = 1.f / (float)NN_;
  float m0 = S9[0]*inv, m1 = S9[1]*inv, m2 = S9[2]*inv;
  float C00 = S9[3]*inv - m0*m0, C01 = S9[4]*inv - m0*m1, C02 = S9[5]*inv - m0*m2;
  float C11 = S9[6]*inv - m1*m1, C12 = S9[7]*inv - m1*m2, C22 = S9[8]*inv - m2*m2;
  float w0 = W1[c], w1 = W1[64+c], w2 = W1[128+c];
  float mean = m0*w0 + m1*w1 + m2*w2 + b1[c];
  float var  = w0*w0*C00 + w1*w1*C11 + w2*w2*C22
             + 2.f*(w0*w1*C01 + w0*w2*C02 + w1*w2*C12);
  float s = g1[c] * rsqrtf(var + EPSV);
  s1[c] = s;
  t1[c] = be1[c] - s*mean + s*b1[c];
}

// ---- GCN2 via MFMA: h1 register-ring + j-stencil agg + 64x64 GEMM, fused BN2 stats ----
#define H1SLICE(ph, js) do { \
  int js_ = (js); \
  _Pragma("unroll") \
  for (int i_ = 0; i_ < 16; i_++){ \
    const float* xp_ = xas + ((size_t)(wl0 + i_) * 25 + js_) * 3; \
    h[ph][i_] = lrelu(fmaf(sS, fmaf(xp_[0], w0c, fmaf(xp_[1], w1c, xp_[2]*w2c)), tT)); \
  } } while(0)

#define AGGW(pm, pc, pp) do { \
  _Pragma("unroll") \
  for (int i_ = 0; i_ < 16; i_++){ \
    float a_ = wgm*h[pm][i_] + wgs*h[pc][i_] + wgp*h[pp][i_]; \
    int row_ = wl0 + i_; \
    *(unsigned short*)(As + row_*128 + ((((lane>>3)) ^ (row_&7))<<4) + ((lane&7)<<1)) = f2bf(a_); \
  } } while(0)

__global__ __launch_bounds__(256) void k_gcn2m(const float* __restrict__ xa,
                                               const float* __restrict__ W1,
                                               const float* __restrict__ s1,
                                               const float* __restrict__ t1,
                                               const float* __restrict__ b2,
                                               const unsigned short* __restrict__ wt2g,
                                               unsigned short* __restrict__ y2t,
                                               float* __restrict__ sum2,
                                               float* __restrict__ sq2){
  __shared__ float xas[4800];          // [l][j][d], contiguous copy
  __shared__ float prm[384];           // W1(192) s1(64) t1(64) b2(64)
  __shared__ char As[8192];            // agg tile [64 l][64 cc] bf16, swizzled
  __shared__ char Bs[8192];            // wt2g tile [64 f][64 cc] bf16, swizzled
  int blk = blockIdx.x;                // 512 = ((b*4)+lq)*2 + jh
  int jh = blk & 1;
  int lq = (blk >> 1) & 3;
  int b  = blk >> 3;
  int l0 = lq << 6;
  int tid = threadIdx.x;
  int w = tid >> 6, lane = tid & 63;

  // stage xas (contiguous 4800 floats)
  const float* xsrc = xa + (size_t)(b * 256 + l0) * 75;
  #pragma unroll
  for (int i = 0; i < 5; i++){
    int idx = tid + (i << 8);
    if (idx < 1200) ((float4*)xas)[idx] = ((const float4*)xsrc)[idx];
  }
  // stage prm
  prm[tid] = (tid < 192) ? W1[tid] : s1[tid - 192];
  if (tid < 128) prm[256 + tid] = (tid < 64) ? t1[tid] : b2[tid - 64];
  // stage Bs via global_load_lds with pre-swizzled source
  #pragma unroll
  for (int i = 0; i < 2; i++){
    int r = (w << 4) + (i << 3) + (lane >> 3);
    int cblk = lane & 7;
    gl16(wt2g + (size_t)r * 64 + (((cblk ^ (r & 7))) << 3),
         Bs + (w << 11) + (i << 10));
  }
  __syncthreads();

  // per-thread hoisted coefficients (ch = lane)
  float w0c = prm[lane], w1c = prm[64 + lane], w2c = prm[128 + lane];
  float sS = prm[192 + lane], tT = prm[256 + lane];
  int wm = w >> 1, wn = w & 1;
  int m0 = (wm << 5) + (lane & 15);
  int n0 = (wn << 5) + (lane & 15);
  int kg = lane >> 4;
  float bias0 = prm[320 + n0], bias1 = prm[320 + n0 + 16];
  int wl0 = w << 4;

  float h[3][16];
  int J0 = jh ? 12 : 0;      // J0 % 3 == 0 in both cases -> static ring phases
  int NJ = jh ? 13 : 12;
  #pragma unroll
  for (int i = 0; i < 16; i++) h[2][i] = 0.f;
  H1SLICE(0, J0);
  if (J0 > 0) H1SLICE(2, J0 - 1);

  float ss0 = 0.f, ss1 = 0.f, qq0 = 0.f, qq1 = 0.f;

  #pragma unroll
  for (int jj = 0; jj < 13; jj++){
    if (jj >= NJ) break;
    int j = J0 + jj;
    // compute slice j+1 into phase (jj+1)%3
    if (j + 1 <= 24){
      switch ((jj + 1) % 3){
        case 0: H1SLICE(0, j + 1); break;
        case 1: H1SLICE(1, j + 1); break;
        case 2: H1SLICE(2, j + 1); break;
      }
    }
    float dj  = (j == 0 || j == 24) ? 2.f : 3.f;
    float rdj = rsqrtf(dj);
    float wgs = 1.f / dj;
    float wgm = (j > 0)  ? rdj * rsqrtf((j == 1)  ? 2.f : 3.f) : 0.f;
    float wgp = (j < 24) ? rdj * rsqrtf((j == 23) ? 2.f : 3.f) : 0.f;
    // aggregate into As (phases: j-1=(jj+2)%3, j=jj%3, j+1=(jj+1)%3)
    switch (jj % 3){
      case 0: AGGW(2, 0, 1); break;
      case 1: AGGW(0, 1, 2); break;
      case 2: AGGW(1, 2, 0); break;
    }
    __syncthreads();
    f32x4 acc[2][2] = {};
    #pragma unroll
    for (int ks = 0; ks < 2; ks++){
      int kb = kg + (ks << 2);
      short8 a0 = *(const short8*)(As + (m0 << 7)        + ((kb ^ (m0 & 7)) << 4));
      short8 a1 = *(const short8*)(As + ((m0 + 16) << 7) + ((kb ^ (m0 & 7)) << 4));
      short8 b0 = *(const short8*)(Bs + (n0 << 7)        + ((kb ^ (n0 & 7)) << 4));
      short8 b1 = *(const short8*)(Bs + ((n0 + 16) << 7) + ((kb ^ (n0 & 7)) << 4));
      acc[0][0] = __builtin_amdgcn_mfma_f32_16x16x32_bf16(a0, b0, acc[0][0], 0, 0, 0);
      acc[0][1] = __builtin_amdgcn_mfma_f32_16x16x32_bf16(a0, b1, acc[0][1], 0, 0, 0);
      acc[1][0] = __builtin_amdgcn_mfma_f32_16x16x32_bf16(a1, b0, acc[1][0], 0, 0, 0);
      acc[1][1] = __builtin_amdgcn_mfma_f32_16x16x32_bf16(a1, b1, acc[1][1], 0, 0, 0);
    }
    __syncthreads();   // As reusable next j
    // epilogue: bias, stats partials, bf16 store
    int rowb = (wm << 5) + ((lane >> 4) << 2);
    #pragma unroll
    for (int mi = 0; mi < 2; mi++){
      #pragma unroll
      for (int ni = 0; ni < 2; ni++){
        float bias = ni ? bias1 : bias0;
        int f = n0 + (ni << 4);
        #pragma unroll
        for (int r = 0; r < 4; r++){
          float v = acc[mi][ni][r] + bias;
          if (ni){ ss1 += v; qq1 += v * v; } else { ss0 += v; qq0 += v * v; }
          int rl = rowb + (mi << 4) + r;
          y2t[(size_t)(b * 258 + l0 + rl + 1) * 1600 + j * 64 + f] = f2bf(v);
        }
      }
    }
  }
  // stats reduce across the 4 kg groups
  ss0 += __shfl_xor(ss0, 16, 64); ss0 += __shfl_xor(ss0, 32, 64);
  ss1 += __shfl_xor(ss1, 16, 64); ss1 += __shfl_xor(ss1, 32, 64);
  qq0 += __shfl_xor(qq0, 16, 64); qq0 += __shfl_xor(qq0, 32, 64);
  qq1 += __shfl_xor(qq1, 16, 64); qq1 += __shfl_xor(qq1, 32, 64);
  if ((lane >> 4) == 0){
    atomicAdd(sum2 + n0, ss0);      atomicAdd(sq2 + n0, qq0);
    atomicAdd(sum2 + n0 + 16, ss1); atomicAdd(sq2 + n0 + 16, qq1);
  }
}

__global__ void k_bnp(const float* __restrict__ sum, const float* __restrict__ sq,
                      const float* __restrict__ g, const float* __restrict__ be,
                      float* __restrict__ sc, float* __restrict__ sh, float inv){
  int c = threadIdx.x;
  float mean = sum[c] * inv;
  float var  = sq[c] * inv - mean * mean;
  float s = g[c] * rsqrtf(var + EPSV);
  sc[c] = s; sh[c] = be[c] - s * mean;
}

// ---- apply BN2+lrelu in place on y2t data rows only (pads stay zero) ----
__global__ __launch_bounds__(256) void k_bnapp2(unsigned short* __restrict__ y2t,
                                                const float* __restrict__ sc2,
                                                const float* __restrict__ sh2){
  for (unsigned idx = blockIdx.x * 256 + threadIdx.x; idx < 3276800u; idx += 524288u){
    unsigned b = idx / 51200u;
    unsigned rem = idx - b * 51200u;
    unsigned l = rem / 200u;
    unsigned cg = rem - l * 200u;
    uint4* p = (uint4*)y2t + ((size_t)b * 258 + l + 1) * 200 + cg;
    unsigned f0 = (cg << 3) & 63u;
    float4 sa = *(const float4*)(sc2 + f0);
    float4 sb = *(const float4*)(sc2 + f0 + 4);
    float4 ha = *(const float4*)(sh2 + f0);
    float4 hb = *(const float4*)(sh2 + f0 + 4);
    float scs[8] = {sa.x,sa.y,sa.z,sa.w,sb.x,sb.y,sb.z,sb.w};
    float shs[8] = {ha.x,ha.y,ha.z,ha.w,hb.x,hb.y,hb.z,hb.w};
    uint4 v = *p;
    unsigned vv[4] = {v.x,v.y,v.z,v.w};
    unsigned r[4];
    #pragma unroll
    for (int i = 0; i < 4; i++){
      float lo = bf2f(vv[i] & 0xffffu);
      float hi = bf2f(vv[i] >> 16);
      lo = lrelu(fmaf(scs[2*i],   lo, shs[2*i]));
      hi = lrelu(fmaf(scs[2*i+1], hi, shs[2*i+1]));
      r[i] = (unsigned)f2bf(lo) | (((unsigned)f2bf(hi)) << 16);
    }
    *p = make_uint4(r[0],r[1],r[2],r[3]);
  }
}

// ---- conv1 as MFMA GEMM + fused stats3; t-order (cc outer, k inner) for L2 tap reuse ----
#define NT_ 75
__global__ __launch_bounds__(256) void k_conv1(const unsigned short* __restrict__ y2t,
                                               const unsigned short* __restrict__ wt1,
                                               const float* __restrict__ cb1,
                                               float* __restrict__ y3,
                                               float* __restrict__ sum3,
                                               float* __restrict__ sq3){
  __shared__ char smem[32768];
  // XCD-aware swizzle: og/lq/b siblings land on the same XCD for L2 dedup
  int bid = blockIdx.x;          // 512
  int blk = ((bid & 7) << 6) | (bid >> 3);
  int b  = blk >> 3;
  int lq = (blk >> 1) & 3;
  int og = blk & 1;
  int l0 = lq << 6;
  int tid = threadIdx.x;
  int w = tid >> 6, lane = tid & 63;
  int wm = w >> 1, wn = w & 1;
  const unsigned short* y2b = y2t + (size_t)b * 412800;
  const unsigned short* wtb = wt1 + (size_t)og * 64 * 1600;

  int rs = (w << 4) + (lane >> 3);
  int cblk = lane & 7;
  int m0 = (wm << 5) + (lane & 15);
  int n0 = (wn << 5) + (lane & 15);
  int kg = lane >> 4;

  f32x4 acc[2][2] = {};

  auto stage = [&](int t, int buf){
    int cc6 = (t * 0x5556) >> 16;          // t / 3 for t < 75
    int k   = t - cc6 * 3;
    int cc  = cc6 << 6;
    const unsigned short* wk = wtb + (size_t)k * 204800;
    #pragma unroll
    for (int i = 0; i < 2; i++){
      int r = rs + (i << 3);
      int sw = (cblk ^ (r & 7)) << 3;
      gl16(y2b + (size_t)(l0 + r + k) * 1600 + cc + sw,
           smem + buf * 16384 + (w << 11) + (i << 10));
      gl16(wk + (size_t)r * 1600 + cc + sw,
           smem + buf * 16384 + 8192 + (w << 11) + (i << 10));
    }
  };

  stage(0, 0);
  __syncthreads();
  #pragma unroll 2
  for (int t = 0; t < NT_; ++t){
    int buf = t & 1;
    if (t + 1 < NT_) stage(t + 1, buf ^ 1);
    const char* Ab = smem + buf * 16384;
    const char* Bb = Ab + 8192;
    #pragma unroll
    for (int ks = 0; ks < 2; ks++){
      int kb = kg + (ks << 2);
      short8 a0 = *(const short8*)(Ab + (m0 << 7)        + ((kb ^ (m0 & 7)) << 4));
      short8 a1 = *(const short8*)(Ab + ((m0 + 16) << 7) + ((kb ^ (m0 & 7)) << 4));
      short8 b0 = *(const short8*)(Bb + (n0 << 7)        + ((kb ^ (n0 & 7)) << 4));
      short8 b1 = *(const short8*)(Bb + ((n0 + 16) << 7) + ((kb ^ (n0 & 7)) << 4));
      acc[0][0] = __builtin_amdgcn_mfma_f32_16x16x32_bf16(a0, b0, acc[0][0], 0, 0, 0);
      acc[0][1] = __builtin_amdgcn_mfma_f32_16x16x32_bf16(a0, b1, acc[0][1], 0, 0, 0);
      acc[1][0] = __builtin_amdgcn_mfma_f32_16x16x32_bf16(a1, b0, acc[1][0], 0, 0, 0);
      acc[1][1] = __builtin_amdgcn_mfma_f32_16x16x32_bf16(a1, b1, acc[1][1], 0, 0, 0);
    }
    __syncthreads();
  }

  int colb = (og << 6) + n0;
  int rowb = l0 + (wm << 5) + ((lane >> 4) << 2);
  float ss0 = 0.f, ss1 = 0.f, qq0 = 0.f, qq1 = 0.f;
  #pragma unroll
  for (int mi = 0; mi < 2; mi++){
    #pragma unroll
    for (int ni = 0; ni < 2; ni++){
      int col = colb + (ni << 4);
      float bias = cb1[col];
      #pragma unroll
      for (int r = 0; r < 4; r++){
        float v = acc[mi][ni][r] + bias;
        if (ni){ ss1 += v; qq1 += v * v; } else { ss0 += v; qq0 += v * v; }
        y3[(size_t)((b << 8) + rowb + (mi << 4) + r) * 128 + col] = v;
      }
    }
  }
  ss0 += __shfl_xor(ss0, 16, 64); ss0 += __shfl_xor(ss0, 32, 64);
  ss1 += __shfl_xor(ss1, 16, 64); ss1 += __shfl_xor(ss1, 32, 64);
  qq0 += __shfl_xor(qq0, 16, 64); qq0 += __shfl_xor(qq0, 32, 64);
  qq1 += __shfl_xor(qq1, 16, 64); qq1 += __shfl_xor(qq1, 32, 64);
  if ((lane >> 4) == 0){
    atomicAdd(sum3 + colb, ss0);      atomicAdd(sq3 + colb, qq0);
    atomicAdd(sum3 + colb + 16, ss1); atomicAdd(sq3 + colb + 16, qq1);
  }
}

// ---- conv2 MFMA + fused BN3/lrelu on A-staging + fused stats4 (h3 buffer removed) ----
__global__ __launch_bounds__(256) void k_conv2(const float* __restrict__ y3,
                                               const float* __restrict__ sc3,
                                               const float* __restrict__ sh3,
                                               const unsigned short* __restrict__ wt2,
                                               const float* __restrict__ cb2,
                                               float* __restrict__ y4,
                                               float* __restrict__ sum4,
                                               float* __restrict__ sq4){
  __shared__ char smem[32768];   // A bf16 swz [64][128] @0 (16KB), B @16384 (16KB)
  int blk = blockIdx.x;          // 256 = 64b * 4lq
  int b = blk >> 2, lq = blk & 3;
  int l0 = lq << 6;
  int tid = threadIdx.x;
  int w = tid >> 6, lane = tid & 63;
  int wm = w >> 1, wn = w & 1;
  // B staging via gl16 (pre-swizzled source)
  #pragma unroll
  for (int i = 0; i < 4; i++){
    int r = (w << 4) + (i << 2) + (lane >> 4);
    int sw = (((lane & 15) ^ (r & 7)) << 3);
    gl16(wt2 + (size_t)r * 128 + sw, smem + 16384 + (w << 12) + (i << 10));
  }
  // A: reg-stage y3 f32, apply BN3+lrelu, pack bf16, swizzled ds_write
  #pragma unroll
  for (int i = 0; i < 4; i++){
    int idx = tid + (i << 8);       // 0..1023 -> row r (64), slot s (16)
    int r = idx >> 4, s = idx & 15;
    const float* src = y3 + (size_t)((b << 8) + l0 + r) * 128 + (s << 3);
    float4 v0 = *(const float4*)(src);
    float4 v1 = *(const float4*)(src + 4);
    float4 c0 = *(const float4*)(sc3 + (s << 3));
    float4 c1 = *(const float4*)(sc3 + (s << 3) + 4);
    float4 h0 = *(const float4*)(sh3 + (s << 3));
    float4 h1 = *(const float4*)(sh3 + (s << 3) + 4);
    uint4 u;
    u.x = (unsigned)f2bf(lrelu(fmaf(c0.x, v0.x, h0.x))) |
          ((unsigned)f2bf(lrelu(fmaf(c0.y, v0.y, h0.y))) << 16);
    u.y = (unsigned)f2bf(lrelu(fmaf(c0.z, v0.z, h0.z))) |
          ((unsigned)f2bf(lrelu(fmaf(c0.w, v0.w, h0.w))) << 16);
    u.z = (unsigned)f2bf(lrelu(fmaf(c1.x, v1.x, h1.x))) |
          ((unsigned)f2bf(lrelu(fmaf(c1.y, v1.y, h1.y))) << 16);
    u.w = (unsigned)f2bf(lrelu(fmaf(c1.z, v1.z, h1.z))) |
          ((unsigned)f2bf(lrelu(fmaf(c1.w, v1.w, h1.w))) << 16);
    *(uint4*)(smem + r * 256 + ((s ^ (r & 7)) << 4)) = u;
  }
  __syncthreads();
  f32x4 acc[2][2] = {};
  int m0 = (wm << 5) + (lane & 15);
  int n0 = (wn << 5) + (lane & 15);
  int kg = lane >> 4;
  const char* Ab = smem;
  const char* Bb = smem + 16384;
  #pragma unroll
  for (int ks = 0; ks < 4; ks++){
    int kb = kg + (ks << 2);
    short8 a0 = *(const short8*)(Ab + (m0 << 8)        + ((kb ^ (m0 & 7)) << 4));
    short8 a1 = *(const short8*)(Ab + ((m0 + 16) << 8) + ((kb ^ (m0 & 7)) << 4));
    short8 b0 = *(const short8*)(Bb + (n0 << 8)        + ((kb ^ (n0 & 7)) << 4));
    short8 b1 = *(const short8*)(Bb + ((n0 + 16) << 8) + ((kb ^ (n0 & 7)) << 4));
    acc[0][0] = __builtin_amdgcn_mfma_f32_16x16x32_bf16(a0, b0, acc[0][0], 0, 0, 0);
    acc[0][1] = __builtin_amdgcn_mfma_f32_16x16x32_bf16(a0, b1, acc[0][1], 0, 0, 0);
    acc[1][0] = __builtin_amdgcn_mfma_f32_16x16x32_bf16(a1, b0, acc[1][0], 0, 0, 0);
    acc[1][1] = __builtin_amdgcn_mfma_f32_16x16x32_bf16(a1, b1, acc[1][1], 0, 0, 0);
  }
  int rowb = l0 + (wm << 5) + ((lane >> 4) << 2);
  float ss0 = 0.f, ss1 = 0.f, qq0 = 0.f, qq1 = 0.f;
  #pragma unroll
  for (int mi = 0; mi < 2; mi++){
    #pragma unroll
    for (int ni = 0; ni < 2; ni++){
      int f = n0 + (ni << 4);
      float bias = cb2[f];
      #pragma unroll
      for (int r = 0; r < 4; r++){
        float v = acc[mi][ni][r] + bias;
        if (ni){ ss1 += v; qq1 += v * v; } else { ss0 += v; qq0 += v * v; }
        y4[(size_t)((b << 8) + rowb + (mi << 4) + r) * 64 + f] = v;
      }
    }
  }
  ss0 += __shfl_xor(ss0, 16, 64); ss0 += __shfl_xor(ss0, 32, 64);
  ss1 += __shfl_xor(ss1, 16, 64); ss1 += __shfl_xor(ss1, 32, 64);
  qq0 += __shfl_xor(qq0, 16, 64); qq0 += __shfl_xor(qq0, 32, 64);
  qq1 += __shfl_xor(qq1, 16, 64); qq1 += __shfl_xor(qq1, 32, 64);
  if ((lane >> 4) == 0){
    atomicAdd(sum4 + n0, ss0);      atomicAdd(sq4 + n0, qq0);
    atomicAdd(sum4 + n0 + 16, ss1); atomicAdd(sq4 + n0 + 16, qq1);
  }
}

// ---- final: out = lrelu(bn4(y4)) ----
__global__ __launch_bounds__(256) void k_final(const float* __restrict__ y4,
                                               const float* __restrict__ sc4,
                                               const float* __restrict__ sh4,
                                               float* __restrict__ out){
  unsigned q = blockIdx.x * 256 + threadIdx.x;
  unsigned f0 = (q & 15) << 2;
  float4 v = ((const float4*)y4)[q];
  float4 sc = *(const float4*)(sc4 + f0);
  float4 sh = *(const float4*)(sh4 + f0);
  v.x = lrelu(fmaf(sc.x, v.x, sh.x));
  v.y = lrelu(fmaf(sc.y, v.y, sh.y));
  v.z = lrelu(fmaf(sc.z, v.z, sh.z));
  v.w = lrelu(fmaf(sc.w, v.w, sh.w));
  ((float4*)out)[q] = v;
}

extern "C" void kernel_launch(void* const* d_in, const int* in_sizes, int n_in,
                              void* d_out, int out_size, void* d_ws, size_t ws_size,
                              hipStream_t stream){
  const float* x    = (const float*)d_in[0];
  const float* W1   = (const float*)d_in[4];
  const float* b1   = (const float*)d_in[5];
  const float* g1   = (const float*)d_in[6];
  const float* be1  = (const float*)d_in[7];
  const float* W2   = (const float*)d_in[8];
  const float* b2   = (const float*)d_in[9];
  const float* g2   = (const float*)d_in[10];
  const float* be2  = (const float*)d_in[11];
  const float* cw1  = (const float*)d_in[12];
  const float* cb1  = (const float*)d_in[13];
  const float* cg1  = (const float*)d_in[14];
  const float* cbe1 = (const float*)d_in[15];
  const float* cw2  = (const float*)d_in[16];
  const float* cb2  = (const float*)d_in[17];
  const float* cg2  = (const float*)d_in[18];
  const float* cbe2 = (const float*)d_in[19];

  char* ws = (char*)d_ws;
  unsigned short* y2t  = (unsigned short*)(ws + WS_Y2T);
  float* xa            = (float*)(ws + WS_XA);
  unsigned short* wt1  = (unsigned short*)(ws + WS_WT1);
  unsigned short* wt2  = (unsigned short*)(ws + WS_WT2);
  unsigned short* wt2g = (unsigned short*)(ws + WS_WT2G);
  float* y3            = (float*)(ws + WS_Y3);
  float* y4            = (float*)(ws + WS_Y4);
  float* st            = (float*)(ws + WS_ST);

  if (ws_size < WS_ST + ST_COUNT * 4) return;

  hipMemsetAsync(st, 0, ST_COUNT * 4, stream);
  k_zpad  <<<64, 256, 0, stream>>>(y2t);
  k_wt    <<<432, 256, 0, stream>>>(cw1, W2, cw2, wt1, wt2, wt2g);
  k_gcn1  <<<1600, 256, 0, stream>>>(x, xa, st + ST_S9);
  k_bn1   <<<1, 64, 0, stream>>>(st + ST_S9, W1, b1, g1, be1, st + ST_S1, st + ST_T1);
  k_gcn2m <<<512, 256, 0, stream>>>(xa, W1, st + ST_S1, st + ST_T1, b2, wt2g,
                                    y2t, st + ST_SUM2, st + ST_SQ2);
  k_bnp   <<<1, 64, 0, stream>>>(st + ST_SUM2, st + ST_SQ2, g2, be2,
                                 st + ST_SC2, st + ST_SH2, 1.f / (float)NN_);
  k_bnapp2<<<2048, 256, 0, stream>>>(y2t, st + ST_SC2, st + ST_SH2);
  k_conv1 <<<512, 256, 0, stream>>>(y2t, wt1, cb1, y3, st + ST_SUM3, st + ST_SQ3);
  k_bnp   <<<1, 128, 0, stream>>>(st + ST_SUM3, st + ST_SQ3, cg1, cbe1,
                                  st + ST_SC3, st + ST_SH3, 1.f / (float)MM_);
  k_conv2 <<<256, 256, 0, stream>>>(y3, st + ST_SC3, st + ST_SH3, wt2, cb2,
                                    y4, st + ST_SUM4, st + ST_SQ4);
  k_bnp   <<<1, 64, 0, stream>>>(st + ST_SUM4, st + ST_SQ4, cg2, cbe2,
                                 st + ST_SC4, st + ST_SH4, 1.f / (float)MM_);
  k_final <<<1024, 256, 0, stream>>>(y4, st + ST_SC4, st + ST_SH4, (float*)d_out);
}